// Round 10
// baseline (456.484 us; speedup 1.0000x reference)
//
#include <hip/hip_runtime.h>
#include <cstdint>

#define N_NODES 20000
#define N_EDGES 320000
#define ALPHA 0.2f
#define GAT_EPS 1e-16f
#define MPAD 20096           // 157 * 128
#define RBLK 157
#define RHI 20               // ceil(157/8)
#define SCAN_BLKS 80
#define BT_ROWS 1152         // 9 col-blocks * 128

typedef __attribute__((ext_vector_type(8))) _Float16 half8;
typedef __attribute__((ext_vector_type(4))) _Float16 half4t;
typedef __attribute__((ext_vector_type(16))) float f32x16;
typedef __attribute__((ext_vector_type(2))) float f32x2;

__device__ __forceinline__ float elu1(float x) { return x > 0.f ? x : __expf(x) - 1.f; }

__device__ __forceinline__ unsigned char f2fp8(float x) {
    return (unsigned char)(__builtin_amdgcn_cvt_pk_fp8_f32(x, 0.f, 0, false) & 0xff);
}

__device__ __forceinline__ void async16(const void* g, void* l) {
    __builtin_amdgcn_global_load_lds(
        (const __attribute__((address_space(1))) unsigned int*)g,
        (__attribute__((address_space(3))) unsigned int*)l, 16, 0, 0);
}

__device__ __forceinline__ float rdlanef(float v, int j) {
    return __int_as_float(__builtin_amdgcn_readlane(__float_as_int(v), j));
}

template <bool HI>
__device__ __forceinline__ f32x2 cvt8(unsigned int u) {
    return __builtin_amdgcn_cvt_pk_f32_fp8((int)u, HI);
}

// ---------------- CSR build ----------------
__global__ void hist_kernel(const int* __restrict__ dst, int* __restrict__ counts, int E) {
    int e = blockIdx.x * blockDim.x + threadIdx.x;
    if (e < E) atomicAdd(&counts[dst[e]], 1);
}

__global__ void scan1_kernel(const int* __restrict__ counts, int* __restrict__ excl,
                             int* __restrict__ partial, int N) {
    __shared__ int sh[256];
    int t = threadIdx.x, b = blockIdx.x;
    int i = b * 256 + t;
    int v = (i < N) ? counts[i] : 0;
    sh[t] = v;
    __syncthreads();
    for (int d = 1; d < 256; d <<= 1) {
        int x = (t >= d) ? sh[t - d] : 0;
        __syncthreads();
        sh[t] += x;
        __syncthreads();
    }
    if (i < N) excl[i] = sh[t] - v;
    if (t == 255) partial[b] = sh[255];
}

__global__ void scan2_kernel(int* __restrict__ partial) {
    __shared__ int sh[128];
    int t = threadIdx.x;
    int v = (t < SCAN_BLKS) ? partial[t] : 0;
    sh[t] = v;
    __syncthreads();
    for (int d = 1; d < 128; d <<= 1) {
        int x = (t >= d) ? sh[t - d] : 0;
        __syncthreads();
        sh[t] += x;
        __syncthreads();
    }
    if (t < SCAN_BLKS) partial[t] = sh[t] - v;
}

__global__ void scan3_kernel(const int* __restrict__ excl, const int* __restrict__ partial,
                             int* __restrict__ rowptr, int* __restrict__ cursor, int N, int E) {
    int t = threadIdx.x, b = blockIdx.x;
    int i = b * 256 + t;
    if (i < N) {
        int v = excl[i] + partial[b];
        rowptr[i] = v;
        cursor[i] = v;
    }
    if (i == 0) rowptr[N] = E;
}

__global__ void scatter_kernel(const int* __restrict__ src, const int* __restrict__ dst,
                               int* __restrict__ cursor, int* __restrict__ esrc, int E) {
    int e = blockIdx.x * blockDim.x + threadIdx.x;
    if (e < E) {
        int p = atomicAdd(&cursor[dst[e]], 1);
        esrc[p] = src[e];
    }
}

// ---------------- packs ----------------
__global__ void pack_x16(const float* __restrict__ x, _Float16* __restrict__ A) {
    int idx = blockIdx.x * 256 + threadIdx.x;   // MPAD*64
    int r = idx >> 6, c = idx & 63;
    float v = (r < N_NODES && c < 50) ? x[r * 50 + c] : 0.f;
    A[idx] = (_Float16)v;
}

__global__ void pack_bt1(const float* __restrict__ W, _Float16* __restrict__ Bt) {
    int idx = blockIdx.x * 256 + threadIdx.x;   // 1024*64
    int c = idx >> 6, k = idx & 63;
    int h = c >> 8, f = c & 255;
    float v = (k < 50) ? W[((size_t)h * 50 + k) * 256 + f] : 0.f;
    Bt[idx] = (_Float16)v;
}

// generic: BT row c -> head h=c/Fpad, col f=c%Fpad; zero for f>=F (alignment pad)
__global__ void pack_bt16(const float* __restrict__ W, _Float16* __restrict__ Bt,
                          int F, int Fpad, int Ctot) {
    int c = blockIdx.y;
    int k = blockIdx.x * blockDim.x + threadIdx.x;
    float v = 0.f;
    if (c < Ctot) {
        int h = c / Fpad, f = c - h * Fpad;
        if (f < F) v = W[(size_t)h * 1024 * F + (size_t)k * F + f];
    }
    Bt[(size_t)c * 1024 + k] = (_Float16)v;
}

// W~ cols appended at BT rows [Nfeat, Nfeat+2H); gridDim.y MUST be 2*H.
__global__ __launch_bounds__(64) void wtilde_kernel(const float* __restrict__ W,
                                                    const float* __restrict__ a,
                                                    _Float16* __restrict__ BT, int Kreal,
                                                    int Kdim, int F, int H, int Nfeat) {
    int k = blockIdx.x, j = blockIdx.y;
    if (j >= 2 * H) return;
    int lane = threadIdx.x;
    int h = j < H ? j : j - H;
    int ao = j < H ? 0 : F;
    float s = 0.f;
    if (k < Kreal) {
        const float* wp = W + ((size_t)h * Kreal + k) * F;
        const float* ap = a + (size_t)h * 2 * F + ao;
        for (int f = lane; f < F; f += 64) s += wp[f] * ap[f];
    }
#pragma unroll
    for (int off = 32; off; off >>= 1) s += __shfl_down(s, off);
    if (lane == 0) BT[(size_t)(Nfeat + j) * Kdim + k] = (_Float16)s;
}

// ---------------- fp16 MFMA GEMM (32x32x16) ----------------
__global__ __launch_bounds__(256) void gemm_f16(const _Float16* __restrict__ A,
                                                const _Float16* __restrict__ BT,
                                                unsigned char* __restrict__ C8,
                                                float* __restrict__ SPRE,
                                                int M, int Nfeat, int ld, int Kdim, int Cblk,
                                                int ldA, int mode) {
    int id = blockIdx.x;
    int xm = id & 7, q = id >> 3;
    int cb = q % Cblk, rh = q / Cblk;
    int rb = rh * 8 + xm;
    if (rb >= RBLK) return;
    __shared__ __align__(16) _Float16 sA[128 * 64];
    __shared__ __align__(16) _Float16 sB[128 * 64];
    int t = threadIdx.x;
    int row0 = rb * 128, col0 = cb * 128;
    int lane = t & 63, wave = t >> 6;
    int wm = wave >> 1, wn = wave & 1;
    int l31 = lane & 31;
    int lhi = lane >> 5;

    int koff = (mode == 1) ? ((cb >> 1) * 64) : 0;
    const _Float16* gA = A + (size_t)row0 * ldA + koff;
    const _Float16* gB = BT + (size_t)col0 * Kdim;

    int sR[4], sgl[4];
#pragma unroll
    for (int i = 0; i < 4; i++) {
        int m = i * 256 + t;
        sR[i] = m >> 3;
        sgl[i] = (m & 7) ^ (sR[i] & 7);
    }

    f32x16 acc[2][2] = {};

    for (int k0 = 0; k0 < Kdim; k0 += 64) {
        __syncthreads();
#pragma unroll
        for (int i = 0; i < 4; i++) {
            const _Float16* pa = gA + (size_t)sR[i] * ldA + k0 + sgl[i] * 8;
            const _Float16* pb = gB + (size_t)sR[i] * Kdim + k0 + sgl[i] * 8;
            async16(pa, sA + (i * 256 + t) * 8);
            async16(pb, sB + (i * 256 + t) * 8);
        }
        __syncthreads();
#pragma unroll
        for (int kk = 0; kk < 4; kk++) {
            int g = kk * 2 + lhi;
            half8 af[2], bf[2];
#pragma unroll
            for (int mt = 0; mt < 2; mt++) {
                int R = wm * 64 + mt * 32 + l31;
                int gp = g ^ (R & 7);
                af[mt] = *(const half8*)(sA + R * 64 + gp * 8);
            }
#pragma unroll
            for (int nt = 0; nt < 2; nt++) {
                int R = wn * 64 + nt * 32 + l31;
                int gp = g ^ (R & 7);
                bf[nt] = *(const half8*)(sB + R * 64 + gp * 8);
            }
#pragma unroll
            for (int mt = 0; mt < 2; mt++)
#pragma unroll
                for (int nt = 0; nt < 2; nt++)
                    acc[mt][nt] = __builtin_amdgcn_mfma_f32_32x32x16_f16(af[mt], bf[nt], acc[mt][nt], 0, 0, 0);
        }
    }

    int cb32 = col0 + wn * 64 + l31;
    int rb32 = row0 + wm * 64 + 4 * lhi;
    if (mode == 1) {
        _Float16* C16 = (_Float16*)C8;
#pragma unroll
        for (int mt = 0; mt < 2; mt++)
#pragma unroll
            for (int nt = 0; nt < 2; nt++) {
                int gc = cb32 + nt * 32;
                if (gc < Nfeat) {
#pragma unroll
                    for (int r = 0; r < 16; r++) {
                        int gr = rb32 + mt * 32 + (r & 3) + 8 * (r >> 2);
                        if (gr < M) C16[(size_t)gr * ld + gc] = (_Float16)elu1(elu1(acc[mt][nt][r]));
                    }
                }
            }
        return;
    }
#pragma unroll
    for (int mt = 0; mt < 2; mt++)
#pragma unroll
        for (int nt = 0; nt < 2; nt++) {
            int gc = cb32 + nt * 32;
            if (gc < Nfeat) {
#pragma unroll
                for (int r = 0; r < 16; r++) {
                    int gr = rb32 + mt * 32 + (r & 3) + 8 * (r >> 2);
                    if (gr < M) C8[(size_t)gr * ld + gc] = f2fp8(acc[mt][nt][r]);
                }
            } else if (gc < Nfeat + 12) {
                int j = gc - Nfeat;
#pragma unroll
                for (int r = 0; r < 16; r++) {
                    int gr = rb32 + mt * 32 + (r & 3) + 8 * (r >> 2);
                    if (gr < M) SPRE[(size_t)j * N_NODES + gr] = acc[mt][nt][r];
                }
            }
        }
}

// ---------------- layer 1: attention + x-aggregation (gather x, L2-resident) ----------
__global__ __launch_bounds__(256) void aggx1_kernel(const int* __restrict__ rowptr,
                                                    const int* __restrict__ esrc,
                                                    const float* __restrict__ SPRE,
                                                    const _Float16* __restrict__ A1,
                                                    _Float16* __restrict__ XB, int N) {
    int n = blockIdx.x;
    int h = threadIdx.x >> 6;
    int lane = threadIdx.x & 63;
    int start = rowptr[n], end = rowptr[n + 1];
    int cnt = end - start;
    const float* ss = SPRE + (size_t)h * N;
    float sd = SPRE[(size_t)(4 + h) * N + n];
    const unsigned char* Wb = (const unsigned char*)A1 + 2 * lane;
    float acc = 0.f;

    if (cnt <= 64) {
        int e = start + lane;
        bool act = e < end;
        int idx = act ? esrc[e] : 0;
        int voff = idx << 7;

        unsigned short wA[8], wB[8], wC[8], wD[8];
        auto ISSUE = [&](unsigned short (&buf)[8], int base) {
#pragma unroll
            for (int u = 0; u < 8; u++) {
                int off = __builtin_amdgcn_readlane(voff, base + u);
                buf[u] = *(const unsigned short*)(Wb + (unsigned)off);
            }
        };
        ISSUE(wA, 0);
        if (cnt > 8)  ISSUE(wB, 8);
        if (cnt > 16) ISSUE(wC, 16);
        if (cnt > 24) ISSUE(wD, 24);

        float sc = -1e30f;
        if (act) {
            sc = ss[idx] + sd;
            sc = sc > 0.f ? sc : ALPHA * sc;
        }
        float m = sc;
#pragma unroll
        for (int off = 1; off < 64; off <<= 1) m = fmaxf(m, __shfl_xor(m, off));
        float ptil = act ? __expf(sc - m) : 0.f;
        float s = ptil;
#pragma unroll
        for (int off = 1; off < 64; off <<= 1) s += __shfl_xor(s, off);
        float p = ptil * (1.f / (s + GAT_EPS));

        auto CONSUME = [&](unsigned short (&buf)[8], int base) {
#pragma unroll
            for (int u = 0; u < 8; u++) {
                float pj = rdlanef(p, base + u);
                acc += pj * (float)(*(const _Float16*)&buf[u]);
            }
        };
        CONSUME(wA, 0);
        if (cnt > 8)  { if (cnt > 32) ISSUE(wA, 32); CONSUME(wB, 8); }
        if (cnt > 16) { if (cnt > 40) ISSUE(wB, 40); CONSUME(wC, 16); }
        if (cnt > 24) { if (cnt > 48) ISSUE(wC, 48); CONSUME(wD, 24); }
        if (cnt > 32) { if (cnt > 56) ISSUE(wD, 56); CONSUME(wA, 32); }
        if (cnt > 40) CONSUME(wB, 40);
        if (cnt > 48) CONSUME(wC, 48);
        if (cnt > 56) CONSUME(wD, 56);
    } else {
        float m = -1e30f, s = 0.f;
        int sidx = 0; float ssc = -1e30f;
        for (int e0 = start; e0 < end; e0 += 64) {
            int e = e0 + lane;
            bool act = e < end;
            int idx = act ? esrc[e] : 0;
            float sc = -1e30f;
            if (act) {
                sc = ss[idx] + sd;
                sc = sc > 0.f ? sc : ALPHA * sc;
            }
            sidx = idx; ssc = sc;
            float mn = fmaxf(m, sc);
            s = s * __expf(m - mn) + (act ? __expf(sc - mn) : 0.f);
            m = mn;
        }
        float lm = m;
#pragma unroll
        for (int off = 1; off < 64; off <<= 1) m = fmaxf(m, __shfl_xor(m, off));
        float ptil = s * __expf(lm - m);
        s = ptil;
#pragma unroll
        for (int off = 1; off < 64; off <<= 1) s += __shfl_xor(s, off);
        float inv = 1.f / (s + GAT_EPS);

        int lastStart = start + (((end - start - 1) >> 6) << 6);
        for (int e0 = start; e0 < end; e0 += 64) {
            int e = e0 + lane;
            bool act = e < end;
            int idx; float p;
            if (e0 == lastStart) {
                idx = sidx;
                p = act ? __expf(ssc - m) * inv : 0.f;
            } else {
                idx = act ? esrc[e] : 0;
                float sc = -1e30f;
                if (act) {
                    sc = ss[idx] + sd;
                    sc = sc > 0.f ? sc : ALPHA * sc;
                }
                p = act ? __expf(sc - m) * inv : 0.f;
            }
            int cn = end - e0; if (cn > 64) cn = 64;
            for (int j = 0; j < cn; j++) {
                int ij = __builtin_amdgcn_readlane(idx, j);
                float pj = rdlanef(p, j);
                unsigned short w = *(const unsigned short*)(Wb + ((size_t)(unsigned)ij << 7));
                acc += pj * (float)(*(const _Float16*)&w);
            }
        }
    }

    XB[(size_t)n * 256 + h * 64 + lane] = (_Float16)acc;
}

// ---------------- attention only: p for H heads -> ATT[h][e] ----------------
__global__ void att_kernel(const int* __restrict__ rowptr, const int* __restrict__ esrc,
                           const float* __restrict__ SPRE, float* __restrict__ ATT,
                           int N, int H) {
    int n = blockIdx.x;
    int h = threadIdx.x >> 6;
    int lane = threadIdx.x & 63;
    if (h >= H) return;
    int start = rowptr[n], end = rowptr[n + 1];
    int cnt = end - start;
    const float* ss = SPRE + (size_t)h * N;
    float sd = SPRE[(size_t)(H + h) * N + n];
    float* ap = ATT + (size_t)h * N_EDGES;

    if (cnt <= 64) {
        int e = start + lane;
        bool act = e < end;
        int idx = act ? esrc[e] : 0;
        float sc = -1e30f;
        if (act) {
            sc = ss[idx] + sd;
            sc = sc > 0.f ? sc : ALPHA * sc;
        }
        float m = sc;
#pragma unroll
        for (int off = 1; off < 64; off <<= 1) m = fmaxf(m, __shfl_xor(m, off));
        float ptil = act ? __expf(sc - m) : 0.f;
        float s = ptil;
#pragma unroll
        for (int off = 1; off < 64; off <<= 1) s += __shfl_xor(s, off);
        if (act) ap[e] = ptil * (1.f / (s + GAT_EPS));
    } else {
        float m = -1e30f, s = 0.f;
        for (int e0 = start; e0 < end; e0 += 64) {
            int e = e0 + lane;
            bool act = e < end;
            int idx = act ? esrc[e] : 0;
            float sc = -1e30f;
            if (act) {
                sc = ss[idx] + sd;
                sc = sc > 0.f ? sc : ALPHA * sc;
            }
            float mn = fmaxf(m, sc);
            s = s * __expf(m - mn) + (act ? __expf(sc - mn) : 0.f);
            m = mn;
        }
        float lm = m;
#pragma unroll
        for (int off = 1; off < 64; off <<= 1) m = fmaxf(m, __shfl_xor(m, off));
        float ptil = s * __expf(lm - m);
        s = ptil;
#pragma unroll
        for (int off = 1; off < 64; off <<= 1) s += __shfl_xor(s, off);
        float inv = 1.f / (s + GAT_EPS);
        for (int e0 = start; e0 < end; e0 += 64) {
            int e = e0 + lane;
            if (e < end) {
                int idx = esrc[e];
                float sc = ss[idx] + sd;
                sc = sc > 0.f ? sc : ALPHA * sc;
                ap[e] = __expf(sc - m) * inv;
            }
        }
    }
}

// ---------------- layer 2 aggregation, XCD-feature-partitioned ----------------
// block id = g*8 + c: chunk c (128 B of the 1 KB Wh row) -> XCD c under round-robin
// dispatch, so each XCD's gather working set is 20096 x 128 B = 2.57 MB -> L2-RESIDENT
// (vs streaming the whole 20 MB table per XCD). Chunks are line-aligned -> XCDs fetch
// disjoint lines. Wave wv of the block handles node g*4+wv; head = c>>1; p from ATT.
__global__ __launch_bounds__(256) void agg256c_kernel(const int* __restrict__ rowptr,
                                                      const int* __restrict__ esrc,
                                                      const float* __restrict__ ATT,
                                                      const unsigned char* __restrict__ WH8,
                                                      _Float16* __restrict__ X16, int N) {
    int id = blockIdx.x;
    int c = id & 7;
    int g = id >> 3;
    int wv = threadIdx.x >> 6;
    int lane = threadIdx.x & 63;
    int n = g * 4 + wv;
    if (n >= N) return;
    int start = rowptr[n], end = rowptr[n + 1];
    int cnt = end - start;
    const float* ap = ATT + (size_t)(c >> 1) * N_EDGES;
    const unsigned char* Wb = WH8 + c * 128 + lane * 2;
    float a0 = 0.f, a1 = 0.f;

    if (cnt <= 64) {
        int e = start + lane;
        bool act = e < end;
        int idx = act ? esrc[e] : 0;
        float p = act ? ap[e] : 0.f;

        unsigned short wA[8], wB[8], wC[8], wD[8];
        auto ISSUE = [&](unsigned short (&buf)[8], int base) {
#pragma unroll
            for (int u = 0; u < 8; u++) {
                int ij = __builtin_amdgcn_readlane(idx, base + u);
                buf[u] = *(const unsigned short*)(Wb + ((size_t)(unsigned)ij << 10));
            }
        };
        ISSUE(wA, 0);
        if (cnt > 8)  ISSUE(wB, 8);
        if (cnt > 16) ISSUE(wC, 16);
        if (cnt > 24) ISSUE(wD, 24);

        auto CONSUME = [&](unsigned short (&buf)[8], int base) {
#pragma unroll
            for (int u = 0; u < 8; u++) {
                float pj = rdlanef(p, base + u);
                f32x2 f = cvt8<false>(buf[u]);
                a0 += pj * f.x; a1 += pj * f.y;
            }
        };
        CONSUME(wA, 0);
        if (cnt > 8)  { if (cnt > 32) ISSUE(wA, 32); CONSUME(wB, 8); }
        if (cnt > 16) { if (cnt > 40) ISSUE(wB, 40); CONSUME(wC, 16); }
        if (cnt > 24) { if (cnt > 48) ISSUE(wC, 48); CONSUME(wD, 24); }
        if (cnt > 32) { if (cnt > 56) ISSUE(wD, 56); CONSUME(wA, 32); }
        if (cnt > 40) CONSUME(wB, 40);
        if (cnt > 48) CONSUME(wC, 48);
        if (cnt > 56) CONSUME(wD, 56);
    } else {
        for (int e0 = start; e0 < end; e0 += 64) {
            int e = e0 + lane;
            bool act = e < end;
            int idx = act ? esrc[e] : 0;
            float p = act ? ap[e] : 0.f;
            int cn = end - e0; if (cn > 64) cn = 64;
            for (int j = 0; j < cn; j++) {
                int ij = __builtin_amdgcn_readlane(idx, j);
                float pj = rdlanef(p, j);
                unsigned short w = *(const unsigned short*)(Wb + ((size_t)(unsigned)ij << 10));
                f32x2 f = cvt8<false>(w);
                a0 += pj * f.x; a1 += pj * f.y;
            }
        }
    }

    size_t o = (size_t)n * 1024 + c * 128 + lane * 2;
    union { unsigned int u; _Float16 hh[2]; } sk, wr;
    sk.u = *(const unsigned int*)(X16 + o);
    wr.hh[0] = (_Float16)elu1(elu1(a0) + (float)sk.hh[0]);
    wr.hh[1] = (_Float16)elu1(elu1(a1) + (float)sk.hh[1]);
    *(unsigned int*)(X16 + o) = wr.u;
}

// ---------------- layer 3 att+agg (r6 broadcast 4-deep, known-best 73.5us) ----------
__global__ __launch_bounds__(384) void attagg726_kernel(const int* __restrict__ rowptr,
                                                        const int* __restrict__ esrc,
                                                        const float* __restrict__ SPRE,
                                                        const unsigned char* __restrict__ WH8,
                                                        float* __restrict__ out, int N) {
    __shared__ float part[6][124];
    int n = blockIdx.x;
    int t = threadIdx.x;
    int h = t >> 6;
    int lane = t & 63;
    int start = rowptr[n], end = rowptr[n + 1];
    int cnt = end - start;
    const float* ss = SPRE + (size_t)h * N;
    float sd = SPRE[(size_t)(6 + h) * N + n];
    const unsigned char* Wb = WH8 + h * 124 + 2 * lane;
    float a0 = 0.f, a1 = 0.f;

    if (cnt <= 64) {
        int e = start + lane;
        bool act = e < end;
        int idx = act ? esrc[e] : 0;

        unsigned short wA[8], wB[8], wC[8], wD[8];
        auto ISSUE = [&](unsigned short (&buf)[8], int base) {
#pragma unroll
            for (int u = 0; u < 8; u++) {
                int ij = __builtin_amdgcn_readlane(idx, base + u);
                buf[u] = *(const unsigned short*)(Wb + (size_t)(unsigned)ij * 768u);
            }
        };
        ISSUE(wA, 0);
        if (cnt > 8)  ISSUE(wB, 8);
        if (cnt > 16) ISSUE(wC, 16);
        if (cnt > 24) ISSUE(wD, 24);

        float sc = -1e30f;
        if (act) {
            sc = ss[idx] + sd;
            sc = sc > 0.f ? sc : ALPHA * sc;
        }
        float m = sc;
#pragma unroll
        for (int off = 1; off < 64; off <<= 1) m = fmaxf(m, __shfl_xor(m, off));
        float ptil = act ? __expf(sc - m) : 0.f;
        float s = ptil;
#pragma unroll
        for (int off = 1; off < 64; off <<= 1) s += __shfl_xor(s, off);
        float p = ptil * (1.f / (s + GAT_EPS));

        auto CONSUME = [&](unsigned short (&buf)[8], int base) {
#pragma unroll
            for (int u = 0; u < 8; u++) {
                float pj = rdlanef(p, base + u);
                f32x2 f = cvt8<false>(buf[u]);
                a0 += pj * f.x; a1 += pj * f.y;
            }
        };
        CONSUME(wA, 0);
        if (cnt > 8)  { if (cnt > 32) ISSUE(wA, 32); CONSUME(wB, 8); }
        if (cnt > 16) { if (cnt > 40) ISSUE(wB, 40); CONSUME(wC, 16); }
        if (cnt > 24) { if (cnt > 48) ISSUE(wC, 48); CONSUME(wD, 24); }
        if (cnt > 32) { if (cnt > 56) ISSUE(wD, 56); CONSUME(wA, 32); }
        if (cnt > 40) CONSUME(wB, 40);
        if (cnt > 48) CONSUME(wC, 48);
        if (cnt > 56) CONSUME(wD, 56);
    } else {
        float m = -1e30f, s = 0.f;
        int sidx = 0; float ssc = -1e30f;
        for (int e0 = start; e0 < end; e0 += 64) {
            int e = e0 + lane;
            bool act = e < end;
            int idx = act ? esrc[e] : 0;
            float sc = -1e30f;
            if (act) {
                sc = ss[idx] + sd;
                sc = sc > 0.f ? sc : ALPHA * sc;
            }
            sidx = idx; ssc = sc;
            float mn = fmaxf(m, sc);
            s = s * __expf(m - mn) + (act ? __expf(sc - mn) : 0.f);
            m = mn;
        }
        float lm = m;
#pragma unroll
        for (int off = 1; off < 64; off <<= 1) m = fmaxf(m, __shfl_xor(m, off));
        float ptil = s * __expf(lm - m);
        s = ptil;
#pragma unroll
        for (int off = 1; off < 64; off <<= 1) s += __shfl_xor(s, off);
        float inv = 1.f / (s + GAT_EPS);

        int lastStart = start + (((end - start - 1) >> 6) << 6);
        for (int e0 = start; e0 < end; e0 += 64) {
            int e = e0 + lane;
            bool act = e < end;
            int idx; float p;
            if (e0 == lastStart) {
                idx = sidx;
                p = act ? __expf(ssc - m) * inv : 0.f;
            } else {
                idx = act ? esrc[e] : 0;
                float sc = -1e30f;
                if (act) {
                    sc = ss[idx] + sd;
                    sc = sc > 0.f ? sc : ALPHA * sc;
                }
                p = act ? __expf(sc - m) * inv : 0.f;
            }
            int cn = end - e0; if (cn > 64) cn = 64;
            if (lane < 62) {
                for (int j = 0; j < cn; j++) {
                    int ij = __builtin_amdgcn_readlane(idx, j);
                    float pj = rdlanef(p, j);
                    unsigned short w = *(const unsigned short*)(Wb + (size_t)ij * 768);
                    f32x2 f = cvt8<false>(w);
                    a0 += pj * f.x; a1 += pj * f.y;
                }
            }
        }
    }

    if (lane < 62) {
        part[h][2 * lane]     = a0;
        part[h][2 * lane + 1] = a1;
    }
    __syncthreads();
    if (t < 121) {
        float tot = (part[0][t] + part[1][t] + part[2][t] +
                     part[3][t] + part[4][t] + part[5][t]) * (1.f / 6.f);
        out[(size_t)n * 121 + t] = 1.f / (1.f + __expf(-tot));
    }
}

extern "C" void kernel_launch(void* const* d_in, const int* in_sizes, int n_in,
                              void* d_out, int out_size, void* d_ws, size_t ws_size,
                              hipStream_t stream) {
    const float* x  = (const float*)d_in[0];
    const int*   ei = (const int*)d_in[1];
    const float* W1 = (const float*)d_in[2];
    const float* a1 = (const float*)d_in[3];
    const float* W2 = (const float*)d_in[4];
    const float* a2 = (const float*)d_in[5];
    const float* W3 = (const float*)d_in[6];
    const float* a3 = (const float*)d_in[7];
    float* out = (float*)d_out;
    const int N = N_NODES, E = N_EDGES;
    const int* src = ei;
    const int* dst = ei + E;

    char* ws = (char*)d_ws;
    size_t off = 0;
    auto alloc = [&](size_t b) { size_t o = off; off += (b + 255) & ~(size_t)255; return o; };
    _Float16* X16  = (_Float16*)(ws + alloc((size_t)MPAD * 1024 * 2));  // x1 then x2 (fp16)
    unsigned char* WH8 = (unsigned char*)(ws + alloc((size_t)MPAD * 1024)); // per-layer Wh (fp8)
    _Float16* BT16 = (_Float16*)(ws + alloc((size_t)BT_ROWS * 1024 * 2));
    _Float16* A1   = (_Float16*)(ws + alloc((size_t)MPAD * 64 * 2));
    _Float16* BT1  = (_Float16*)(ws + alloc((size_t)BT_ROWS * 64 * 2));
    _Float16* XB   = (_Float16*)(ws + alloc((size_t)MPAD * 256 * 2));  // layer-1 xbar
    _Float16* BTS  = (_Float16*)(ws + alloc((size_t)128 * 64 * 2));    // layer-1 score cols
    float* SPRE   = (float*)(ws + alloc((size_t)12 * N * 4));
    float* ATT    = (float*)(ws + alloc((size_t)4 * E * 4));
    int*   rowptr = (int*)(ws + alloc((size_t)(N + 1) * 4));
    int*   cursor = (int*)(ws + alloc((size_t)N * 4));
    int*   counts = (int*)(ws + alloc((size_t)N * 4));
    int*   excl   = (int*)(ws + alloc((size_t)N * 4));
    int*   partial= (int*)(ws + alloc((size_t)SCAN_BLKS * 4));
    int*   esrc   = (int*)(ws + alloc((size_t)E * 4));

    // CSR by dst
    hipMemsetAsync(counts, 0, (size_t)N * 4, stream);
    hist_kernel<<<(E + 255) / 256, 256, 0, stream>>>(dst, counts, E);
    scan1_kernel<<<SCAN_BLKS, 256, 0, stream>>>(counts, excl, partial, N);
    scan2_kernel<<<1, 128, 0, stream>>>(partial);
    scan3_kernel<<<SCAN_BLKS, 256, 0, stream>>>(excl, partial, rowptr, cursor, N, E);
    scatter_kernel<<<(E + 255) / 256, 256, 0, stream>>>(src, dst, cursor, esrc, E);
    hipMemsetAsync(X16 + (size_t)N * 1024, 0, (size_t)(MPAD - N) * 1024 * 2, stream);
    hipMemsetAsync(XB + (size_t)N * 256, 0, (size_t)(MPAD - N) * 256 * 2, stream);

    // ---- layer 1: scores from x@Wtil; aggregate x (L2-resident); block-diag GEMM ----
    pack_x16<<<MPAD * 64 / 256, 256, 0, stream>>>(x, A1);
    pack_bt1<<<1024 * 64 / 256, 256, 0, stream>>>(W1, BT1);
    wtilde_kernel<<<dim3(64, 8), 64, 0, stream>>>(W1, a1, BTS, 50, 64, 256, 4, 0);
    gemm_f16<<<8 * RHI * 1, 256, 0, stream>>>(A1, BTS, WH8, SPRE, N, 0, 1024, 64, 1, 64, 0);
    aggx1_kernel<<<N, 256, 0, stream>>>(rowptr, esrc, SPRE, A1, XB, N);
    gemm_f16<<<8 * RHI * 8, 256, 0, stream>>>(XB, BT1, (unsigned char*)X16, SPRE, N, 1024, 1024, 64, 8, 256, 1);

    // ---- layer 2: 1024 -> 4x256 concat + skip; att pass + XCD-chunked aggregation ----
    pack_bt16<<<dim3(4, 1024), 256, 0, stream>>>(W2, BT16, 256, 256, 1024);
    wtilde_kernel<<<dim3(1024, 8), 64, 0, stream>>>(W2, a2, BT16, 1024, 1024, 256, 4, 1024);
    gemm_f16<<<8 * RHI * 9, 256, 0, stream>>>(X16, BT16, WH8, SPRE, N, 1024, 1024, 1024, 9, 1024, 0);
    att_kernel<<<N, 256, 0, stream>>>(rowptr, esrc, SPRE, ATT, N, 4);
    agg256c_kernel<<<(N / 4) * 8, 256, 0, stream>>>(rowptr, esrc, ATT, WH8, X16, N);

    // ---- layer 3: 1024 -> 6x121 (stride 124, zero-padded), mean + sigmoid ----
    pack_bt16<<<dim3(4, 744), 256, 0, stream>>>(W3, BT16, 121, 124, 744);
    wtilde_kernel<<<dim3(1024, 12), 64, 0, stream>>>(W3, a3, BT16, 1024, 1024, 121, 6, 744);
    gemm_f16<<<8 * RHI * 6, 256, 0, stream>>>(X16, BT16, WH8, SPRE, N, 744, 768, 1024, 6, 1024, 0);
    attagg726_kernel<<<N, 384, 0, stream>>>(rowptr, esrc, SPRE, WH8, out, N);
}

// Round 11
// 424.167 us; speedup vs baseline: 1.0762x; 1.0762x over previous
//
#include <hip/hip_runtime.h>
#include <cstdint>

#define N_NODES 20000
#define N_EDGES 320000
#define ALPHA 0.2f
#define GAT_EPS 1e-16f
#define MPAD 20096           // 157 * 128
#define RBLK 157
#define RHI 20               // ceil(157/8)
#define SCAN_BLKS 80
#define BT_ROWS 1152         // 9 col-blocks * 128

typedef __attribute__((ext_vector_type(8))) _Float16 half8;
typedef __attribute__((ext_vector_type(4))) _Float16 half4t;
typedef __attribute__((ext_vector_type(16))) float f32x16;
typedef __attribute__((ext_vector_type(2))) float f32x2;

__device__ __forceinline__ float elu1(float x) { return x > 0.f ? x : __expf(x) - 1.f; }

__device__ __forceinline__ unsigned char f2fp8(float x) {
    return (unsigned char)(__builtin_amdgcn_cvt_pk_fp8_f32(x, 0.f, 0, false) & 0xff);
}

__device__ __forceinline__ void async16(const void* g, void* l) {
    __builtin_amdgcn_global_load_lds(
        (const __attribute__((address_space(1))) unsigned int*)g,
        (__attribute__((address_space(3))) unsigned int*)l, 16, 0, 0);
}

__device__ __forceinline__ float rdlanef(float v, int j) {
    return __int_as_float(__builtin_amdgcn_readlane(__float_as_int(v), j));
}

template <bool HI>
__device__ __forceinline__ f32x2 cvt8(unsigned int u) {
    return __builtin_amdgcn_cvt_pk_f32_fp8((int)u, HI);
}

// ---------------- CSR build ----------------
__global__ void hist_kernel(const int* __restrict__ dst, int* __restrict__ counts, int E) {
    int e = blockIdx.x * blockDim.x + threadIdx.x;
    if (e < E) atomicAdd(&counts[dst[e]], 1);
}

__global__ void scan1_kernel(const int* __restrict__ counts, int* __restrict__ excl,
                             int* __restrict__ partial, int N) {
    __shared__ int sh[256];
    int t = threadIdx.x, b = blockIdx.x;
    int i = b * 256 + t;
    int v = (i < N) ? counts[i] : 0;
    sh[t] = v;
    __syncthreads();
    for (int d = 1; d < 256; d <<= 1) {
        int x = (t >= d) ? sh[t - d] : 0;
        __syncthreads();
        sh[t] += x;
        __syncthreads();
    }
    if (i < N) excl[i] = sh[t] - v;
    if (t == 255) partial[b] = sh[255];
}

__global__ void scan2_kernel(int* __restrict__ partial) {
    __shared__ int sh[128];
    int t = threadIdx.x;
    int v = (t < SCAN_BLKS) ? partial[t] : 0;
    sh[t] = v;
    __syncthreads();
    for (int d = 1; d < 128; d <<= 1) {
        int x = (t >= d) ? sh[t - d] : 0;
        __syncthreads();
        sh[t] += x;
        __syncthreads();
    }
    if (t < SCAN_BLKS) partial[t] = sh[t] - v;
}

__global__ void scan3_kernel(const int* __restrict__ excl, const int* __restrict__ partial,
                             int* __restrict__ rowptr, int* __restrict__ cursor, int N, int E) {
    int t = threadIdx.x, b = blockIdx.x;
    int i = b * 256 + t;
    if (i < N) {
        int v = excl[i] + partial[b];
        rowptr[i] = v;
        cursor[i] = v;
    }
    if (i == 0) rowptr[N] = E;
}

__global__ void scatter_kernel(const int* __restrict__ src, const int* __restrict__ dst,
                               int* __restrict__ cursor, int* __restrict__ esrc, int E) {
    int e = blockIdx.x * blockDim.x + threadIdx.x;
    if (e < E) {
        int p = atomicAdd(&cursor[dst[e]], 1);
        esrc[p] = src[e];
    }
}

// ---------------- packs ----------------
__global__ void pack_x16(const float* __restrict__ x, _Float16* __restrict__ A) {
    int idx = blockIdx.x * 256 + threadIdx.x;   // MPAD*64
    int r = idx >> 6, c = idx & 63;
    float v = (r < N_NODES && c < 50) ? x[r * 50 + c] : 0.f;
    A[idx] = (_Float16)v;
}

__global__ void pack_bt1(const float* __restrict__ W, _Float16* __restrict__ Bt) {
    int idx = blockIdx.x * 256 + threadIdx.x;   // 1024*64
    int c = idx >> 6, k = idx & 63;
    int h = c >> 8, f = c & 255;
    float v = (k < 50) ? W[((size_t)h * 50 + k) * 256 + f] : 0.f;
    Bt[idx] = (_Float16)v;
}

// generic: BT row c -> head h=c/Fpad, col f=c%Fpad; zero for f>=F (alignment pad)
__global__ void pack_bt16(const float* __restrict__ W, _Float16* __restrict__ Bt,
                          int F, int Fpad, int Ctot) {
    int c = blockIdx.y;
    int k = blockIdx.x * blockDim.x + threadIdx.x;
    float v = 0.f;
    if (c < Ctot) {
        int h = c / Fpad, f = c - h * Fpad;
        if (f < F) v = W[(size_t)h * 1024 * F + (size_t)k * F + f];
    }
    Bt[(size_t)c * 1024 + k] = (_Float16)v;
}

// W~ cols appended at BT rows [Nfeat, Nfeat+2H); gridDim.y MUST be 2*H.
__global__ __launch_bounds__(64) void wtilde_kernel(const float* __restrict__ W,
                                                    const float* __restrict__ a,
                                                    _Float16* __restrict__ BT, int Kreal,
                                                    int Kdim, int F, int H, int Nfeat) {
    int k = blockIdx.x, j = blockIdx.y;
    if (j >= 2 * H) return;
    int lane = threadIdx.x;
    int h = j < H ? j : j - H;
    int ao = j < H ? 0 : F;
    float s = 0.f;
    if (k < Kreal) {
        const float* wp = W + ((size_t)h * Kreal + k) * F;
        const float* ap = a + (size_t)h * 2 * F + ao;
        for (int f = lane; f < F; f += 64) s += wp[f] * ap[f];
    }
#pragma unroll
    for (int off = 32; off; off >>= 1) s += __shfl_down(s, off);
    if (lane == 0) BT[(size_t)(Nfeat + j) * Kdim + k] = (_Float16)s;
}

// ---------------- fp16 MFMA GEMM (32x32x16) ----------------
__global__ __launch_bounds__(256) void gemm_f16(const _Float16* __restrict__ A,
                                                const _Float16* __restrict__ BT,
                                                unsigned char* __restrict__ C8,
                                                float* __restrict__ SPRE,
                                                int M, int Nfeat, int ld, int Kdim, int Cblk,
                                                int ldA, int mode) {
    int id = blockIdx.x;
    int xm = id & 7, q = id >> 3;
    int cb = q % Cblk, rh = q / Cblk;
    int rb = rh * 8 + xm;
    if (rb >= RBLK) return;
    __shared__ __align__(16) _Float16 sA[128 * 64];
    __shared__ __align__(16) _Float16 sB[128 * 64];
    int t = threadIdx.x;
    int row0 = rb * 128, col0 = cb * 128;
    int lane = t & 63, wave = t >> 6;
    int wm = wave >> 1, wn = wave & 1;
    int l31 = lane & 31;
    int lhi = lane >> 5;

    int koff = (mode == 1) ? ((cb >> 1) * 64) : 0;
    const _Float16* gA = A + (size_t)row0 * ldA + koff;
    const _Float16* gB = BT + (size_t)col0 * Kdim;

    int sR[4], sgl[4];
#pragma unroll
    for (int i = 0; i < 4; i++) {
        int m = i * 256 + t;
        sR[i] = m >> 3;
        sgl[i] = (m & 7) ^ (sR[i] & 7);
    }

    f32x16 acc[2][2] = {};

    for (int k0 = 0; k0 < Kdim; k0 += 64) {
        __syncthreads();
#pragma unroll
        for (int i = 0; i < 4; i++) {
            const _Float16* pa = gA + (size_t)sR[i] * ldA + k0 + sgl[i] * 8;
            const _Float16* pb = gB + (size_t)sR[i] * Kdim + k0 + sgl[i] * 8;
            async16(pa, sA + (i * 256 + t) * 8);
            async16(pb, sB + (i * 256 + t) * 8);
        }
        __syncthreads();
#pragma unroll
        for (int kk = 0; kk < 4; kk++) {
            int g = kk * 2 + lhi;
            half8 af[2], bf[2];
#pragma unroll
            for (int mt = 0; mt < 2; mt++) {
                int R = wm * 64 + mt * 32 + l31;
                int gp = g ^ (R & 7);
                af[mt] = *(const half8*)(sA + R * 64 + gp * 8);
            }
#pragma unroll
            for (int nt = 0; nt < 2; nt++) {
                int R = wn * 64 + nt * 32 + l31;
                int gp = g ^ (R & 7);
                bf[nt] = *(const half8*)(sB + R * 64 + gp * 8);
            }
#pragma unroll
            for (int mt = 0; mt < 2; mt++)
#pragma unroll
                for (int nt = 0; nt < 2; nt++)
                    acc[mt][nt] = __builtin_amdgcn_mfma_f32_32x32x16_f16(af[mt], bf[nt], acc[mt][nt], 0, 0, 0);
        }
    }

    int cb32 = col0 + wn * 64 + l31;
    int rb32 = row0 + wm * 64 + 4 * lhi;
    if (mode == 1) {
        _Float16* C16 = (_Float16*)C8;
#pragma unroll
        for (int mt = 0; mt < 2; mt++)
#pragma unroll
            for (int nt = 0; nt < 2; nt++) {
                int gc = cb32 + nt * 32;
                if (gc < Nfeat) {
#pragma unroll
                    for (int r = 0; r < 16; r++) {
                        int gr = rb32 + mt * 32 + (r & 3) + 8 * (r >> 2);
                        if (gr < M) C16[(size_t)gr * ld + gc] = (_Float16)elu1(elu1(acc[mt][nt][r]));
                    }
                }
            }
        return;
    }
#pragma unroll
    for (int mt = 0; mt < 2; mt++)
#pragma unroll
        for (int nt = 0; nt < 2; nt++) {
            int gc = cb32 + nt * 32;
            if (gc < Nfeat) {
#pragma unroll
                for (int r = 0; r < 16; r++) {
                    int gr = rb32 + mt * 32 + (r & 3) + 8 * (r >> 2);
                    if (gr < M) C8[(size_t)gr * ld + gc] = f2fp8(acc[mt][nt][r]);
                }
            } else if (gc < Nfeat + 12) {
                int j = gc - Nfeat;
#pragma unroll
                for (int r = 0; r < 16; r++) {
                    int gr = rb32 + mt * 32 + (r & 3) + 8 * (r >> 2);
                    if (gr < M) SPRE[(size_t)j * N_NODES + gr] = acc[mt][nt][r];
                }
            }
        }
}

// ---------------- layer 1: attention + x-aggregation (gather x, L2-resident) ----------
// micro-opts (r11): score gather issued before ISSUE burst; setprio(1) around CONSUME.
__global__ __launch_bounds__(256) void aggx1_kernel(const int* __restrict__ rowptr,
                                                    const int* __restrict__ esrc,
                                                    const float* __restrict__ SPRE,
                                                    const _Float16* __restrict__ A1,
                                                    _Float16* __restrict__ XB, int N) {
    int n = blockIdx.x;
    int h = threadIdx.x >> 6;
    int lane = threadIdx.x & 63;
    int start = rowptr[n], end = rowptr[n + 1];
    int cnt = end - start;
    const float* ss = SPRE + (size_t)h * N;
    float sd = SPRE[(size_t)(4 + h) * N + n];
    const unsigned char* Wb = (const unsigned char*)A1 + 2 * lane;
    float acc = 0.f;

    if (cnt <= 64) {
        int e = start + lane;
        bool act = e < end;
        int idx = act ? esrc[e] : 0;
        float sv = ss[idx];              // early score gather (hides under ISSUE burst)
        int voff = idx << 7;

        unsigned short wA[8], wB[8], wC[8], wD[8];
        auto ISSUE = [&](unsigned short (&buf)[8], int base) {
#pragma unroll
            for (int u = 0; u < 8; u++) {
                int off = __builtin_amdgcn_readlane(voff, base + u);
                buf[u] = *(const unsigned short*)(Wb + (unsigned)off);
            }
        };
        ISSUE(wA, 0);
        if (cnt > 8)  ISSUE(wB, 8);
        if (cnt > 16) ISSUE(wC, 16);
        if (cnt > 24) ISSUE(wD, 24);

        float sc = -1e30f;
        if (act) {
            sc = sv + sd;
            sc = sc > 0.f ? sc : ALPHA * sc;
        }
        float m = sc;
#pragma unroll
        for (int off = 1; off < 64; off <<= 1) m = fmaxf(m, __shfl_xor(m, off));
        float ptil = act ? __expf(sc - m) : 0.f;
        float s = ptil;
#pragma unroll
        for (int off = 1; off < 64; off <<= 1) s += __shfl_xor(s, off);
        float p = ptil * (1.f / (s + GAT_EPS));

        auto CONSUME = [&](unsigned short (&buf)[8], int base) {
#pragma unroll
            for (int u = 0; u < 8; u++) {
                float pj = rdlanef(p, base + u);
                acc += pj * (float)(*(const _Float16*)&buf[u]);
            }
        };
        __builtin_amdgcn_s_setprio(1);
        CONSUME(wA, 0);
        if (cnt > 8)  { if (cnt > 32) ISSUE(wA, 32); CONSUME(wB, 8); }
        if (cnt > 16) { if (cnt > 40) ISSUE(wB, 40); CONSUME(wC, 16); }
        if (cnt > 24) { if (cnt > 48) ISSUE(wC, 48); CONSUME(wD, 24); }
        if (cnt > 32) { if (cnt > 56) ISSUE(wD, 56); CONSUME(wA, 32); }
        if (cnt > 40) CONSUME(wB, 40);
        if (cnt > 48) CONSUME(wC, 48);
        if (cnt > 56) CONSUME(wD, 56);
        __builtin_amdgcn_s_setprio(0);
    } else {
        float m = -1e30f, s = 0.f;
        int sidx = 0; float ssc = -1e30f;
        for (int e0 = start; e0 < end; e0 += 64) {
            int e = e0 + lane;
            bool act = e < end;
            int idx = act ? esrc[e] : 0;
            float sc = -1e30f;
            if (act) {
                sc = ss[idx] + sd;
                sc = sc > 0.f ? sc : ALPHA * sc;
            }
            sidx = idx; ssc = sc;
            float mn = fmaxf(m, sc);
            s = s * __expf(m - mn) + (act ? __expf(sc - mn) : 0.f);
            m = mn;
        }
        float lm = m;
#pragma unroll
        for (int off = 1; off < 64; off <<= 1) m = fmaxf(m, __shfl_xor(m, off));
        float ptil = s * __expf(lm - m);
        s = ptil;
#pragma unroll
        for (int off = 1; off < 64; off <<= 1) s += __shfl_xor(s, off);
        float inv = 1.f / (s + GAT_EPS);

        int lastStart = start + (((end - start - 1) >> 6) << 6);
        for (int e0 = start; e0 < end; e0 += 64) {
            int e = e0 + lane;
            bool act = e < end;
            int idx; float p;
            if (e0 == lastStart) {
                idx = sidx;
                p = act ? __expf(ssc - m) * inv : 0.f;
            } else {
                idx = act ? esrc[e] : 0;
                float sc = -1e30f;
                if (act) {
                    sc = ss[idx] + sd;
                    sc = sc > 0.f ? sc : ALPHA * sc;
                }
                p = act ? __expf(sc - m) * inv : 0.f;
            }
            int cn = end - e0; if (cn > 64) cn = 64;
            for (int j = 0; j < cn; j++) {
                int ij = __builtin_amdgcn_readlane(idx, j);
                float pj = rdlanef(p, j);
                unsigned short w = *(const unsigned short*)(Wb + ((size_t)(unsigned)ij << 7));
                acc += pj * (float)(*(const _Float16*)&w);
            }
        }
    }

    XB[(size_t)n * 256 + h * 64 + lane] = (_Float16)acc;
}

// ---------------- layer 2 att+agg (fused broadcast 4-deep, r7 structure) ----------
// micro-opts (r11): skip-read prefetch at entry; score gather before ISSUE; setprio.
__global__ __launch_bounds__(256) void attagg256_kernel(const int* __restrict__ rowptr,
                                                        const int* __restrict__ esrc,
                                                        const float* __restrict__ SPRE,
                                                        const unsigned char* __restrict__ WH8,
                                                        _Float16* __restrict__ X16,
                                                        int use_skip, int N) {
    int n = blockIdx.x;
    int h = threadIdx.x >> 6;
    int lane = threadIdx.x & 63;
    int start = rowptr[n], end = rowptr[n + 1];
    int cnt = end - start;
    const float* ss = SPRE + (size_t)h * N;
    float sd = SPRE[(size_t)(4 + h) * N + n];
    const unsigned char* Wb = WH8 + h * 256 + lane * 4;
    size_t o = (size_t)n * 1024 + h * 256 + lane * 4;
    half4t sk = {};
    if (use_skip) sk = *(const half4t*)(X16 + o);   // prefetch skip (hides ~600cy)
    float a0 = 0.f, a1 = 0.f, a2 = 0.f, a3 = 0.f;

    if (cnt <= 64) {
        int e = start + lane;
        bool act = e < end;
        int idx = act ? esrc[e] : 0;
        float sv = ss[idx];              // early score gather

        unsigned int wA[8], wB[8], wC[8], wD[8];
        auto ISSUE = [&](unsigned int (&buf)[8], int base) {
#pragma unroll
            for (int u = 0; u < 8; u++) {
                int ij = __builtin_amdgcn_readlane(idx, base + u);
                buf[u] = *(const unsigned int*)(Wb + ((size_t)(unsigned)ij << 10));
            }
        };
        ISSUE(wA, 0);
        if (cnt > 8)  ISSUE(wB, 8);
        if (cnt > 16) ISSUE(wC, 16);
        if (cnt > 24) ISSUE(wD, 24);

        float sc = -1e30f;
        if (act) {
            sc = sv + sd;
            sc = sc > 0.f ? sc : ALPHA * sc;
        }
        float m = sc;
#pragma unroll
        for (int off = 1; off < 64; off <<= 1) m = fmaxf(m, __shfl_xor(m, off));
        float ptil = act ? __expf(sc - m) : 0.f;
        float s = ptil;
#pragma unroll
        for (int off = 1; off < 64; off <<= 1) s += __shfl_xor(s, off);
        float p = ptil * (1.f / (s + GAT_EPS));

        auto CONSUME = [&](unsigned int (&buf)[8], int base) {
#pragma unroll
            for (int u = 0; u < 8; u++) {
                float pj = rdlanef(p, base + u);
                f32x2 lo = cvt8<false>(buf[u]);
                f32x2 hi = cvt8<true>(buf[u]);
                a0 += pj * lo.x; a1 += pj * lo.y; a2 += pj * hi.x; a3 += pj * hi.y;
            }
        };
        __builtin_amdgcn_s_setprio(1);
        CONSUME(wA, 0);
        if (cnt > 8)  { if (cnt > 32) ISSUE(wA, 32); CONSUME(wB, 8); }
        if (cnt > 16) { if (cnt > 40) ISSUE(wB, 40); CONSUME(wC, 16); }
        if (cnt > 24) { if (cnt > 48) ISSUE(wC, 48); CONSUME(wD, 24); }
        if (cnt > 32) { if (cnt > 56) ISSUE(wD, 56); CONSUME(wA, 32); }
        if (cnt > 40) CONSUME(wB, 40);
        if (cnt > 48) CONSUME(wC, 48);
        if (cnt > 56) CONSUME(wD, 56);
        __builtin_amdgcn_s_setprio(0);
    } else {
        float m = -1e30f, s = 0.f;
        int sidx = 0; float ssc = -1e30f;
        for (int e0 = start; e0 < end; e0 += 64) {
            int e = e0 + lane;
            bool act = e < end;
            int idx = act ? esrc[e] : 0;
            float sc = -1e30f;
            if (act) {
                sc = ss[idx] + sd;
                sc = sc > 0.f ? sc : ALPHA * sc;
            }
            sidx = idx; ssc = sc;
            float mn = fmaxf(m, sc);
            s = s * __expf(m - mn) + (act ? __expf(sc - mn) : 0.f);
            m = mn;
        }
        float lm = m;
#pragma unroll
        for (int off = 1; off < 64; off <<= 1) m = fmaxf(m, __shfl_xor(m, off));
        float ptil = s * __expf(lm - m);
        s = ptil;
#pragma unroll
        for (int off = 1; off < 64; off <<= 1) s += __shfl_xor(s, off);
        float inv = 1.f / (s + GAT_EPS);

        int lastStart = start + (((end - start - 1) >> 6) << 6);
        for (int e0 = start; e0 < end; e0 += 64) {
            int e = e0 + lane;
            bool act = e < end;
            int idx; float p;
            if (e0 == lastStart) {
                idx = sidx;
                p = act ? __expf(ssc - m) * inv : 0.f;
            } else {
                idx = act ? esrc[e] : 0;
                float sc = -1e30f;
                if (act) {
                    sc = ss[idx] + sd;
                    sc = sc > 0.f ? sc : ALPHA * sc;
                }
                p = act ? __expf(sc - m) * inv : 0.f;
            }
            int cn = end - e0; if (cn > 64) cn = 64;
            for (int j = 0; j < cn; j++) {
                int ij = __builtin_amdgcn_readlane(idx, j);
                float pj = rdlanef(p, j);
                unsigned int w = *(const unsigned int*)(Wb + (size_t)ij * 1024);
                f32x2 lo = cvt8<false>(w);
                f32x2 hi = cvt8<true>(w);
                a0 += pj * lo.x; a1 += pj * lo.y; a2 += pj * hi.x; a3 += pj * hi.y;
            }
        }
    }

    float v0, v1, v2, v3;
    if (use_skip) {
        v0 = elu1(elu1(a0) + (float)sk.x);
        v1 = elu1(elu1(a1) + (float)sk.y);
        v2 = elu1(elu1(a2) + (float)sk.z);
        v3 = elu1(elu1(a3) + (float)sk.w);
    } else {
        v0 = elu1(elu1(a0)); v1 = elu1(elu1(a1));
        v2 = elu1(elu1(a2)); v3 = elu1(elu1(a3));
    }
    half4t r;
    r.x = (_Float16)v0; r.y = (_Float16)v1; r.z = (_Float16)v2; r.w = (_Float16)v3;
    *(half4t*)(X16 + o) = r;
}

// ---------------- layer 3 att+agg (broadcast 4-deep, known-best) ----------
__global__ __launch_bounds__(384) void attagg726_kernel(const int* __restrict__ rowptr,
                                                        const int* __restrict__ esrc,
                                                        const float* __restrict__ SPRE,
                                                        const unsigned char* __restrict__ WH8,
                                                        float* __restrict__ out, int N) {
    __shared__ float part[6][124];
    int n = blockIdx.x;
    int t = threadIdx.x;
    int h = t >> 6;
    int lane = t & 63;
    int start = rowptr[n], end = rowptr[n + 1];
    int cnt = end - start;
    const float* ss = SPRE + (size_t)h * N;
    float sd = SPRE[(size_t)(6 + h) * N + n];
    const unsigned char* Wb = WH8 + h * 124 + 2 * lane;
    float a0 = 0.f, a1 = 0.f;

    if (cnt <= 64) {
        int e = start + lane;
        bool act = e < end;
        int idx = act ? esrc[e] : 0;
        float sv = ss[idx];              // early score gather

        unsigned short wA[8], wB[8], wC[8], wD[8];
        auto ISSUE = [&](unsigned short (&buf)[8], int base) {
#pragma unroll
            for (int u = 0; u < 8; u++) {
                int ij = __builtin_amdgcn_readlane(idx, base + u);
                buf[u] = *(const unsigned short*)(Wb + (size_t)(unsigned)ij * 768u);
            }
        };
        ISSUE(wA, 0);
        if (cnt > 8)  ISSUE(wB, 8);
        if (cnt > 16) ISSUE(wC, 16);
        if (cnt > 24) ISSUE(wD, 24);

        float sc = -1e30f;
        if (act) {
            sc = sv + sd;
            sc = sc > 0.f ? sc : ALPHA * sc;
        }
        float m = sc;
#pragma unroll
        for (int off = 1; off < 64; off <<= 1) m = fmaxf(m, __shfl_xor(m, off));
        float ptil = act ? __expf(sc - m) : 0.f;
        float s = ptil;
#pragma unroll
        for (int off = 1; off < 64; off <<= 1) s += __shfl_xor(s, off);
        float p = ptil * (1.f / (s + GAT_EPS));

        auto CONSUME = [&](unsigned short (&buf)[8], int base) {
#pragma unroll
            for (int u = 0; u < 8; u++) {
                float pj = rdlanef(p, base + u);
                f32x2 f = cvt8<false>(buf[u]);
                a0 += pj * f.x; a1 += pj * f.y;
            }
        };
        __builtin_amdgcn_s_setprio(1);
        CONSUME(wA, 0);
        if (cnt > 8)  { if (cnt > 32) ISSUE(wA, 32); CONSUME(wB, 8); }
        if (cnt > 16) { if (cnt > 40) ISSUE(wB, 40); CONSUME(wC, 16); }
        if (cnt > 24) { if (cnt > 48) ISSUE(wC, 48); CONSUME(wD, 24); }
        if (cnt > 32) { if (cnt > 56) ISSUE(wD, 56); CONSUME(wA, 32); }
        if (cnt > 40) CONSUME(wB, 40);
        if (cnt > 48) CONSUME(wC, 48);
        if (cnt > 56) CONSUME(wD, 56);
        __builtin_amdgcn_s_setprio(0);
    } else {
        float m = -1e30f, s = 0.f;
        int sidx = 0; float ssc = -1e30f;
        for (int e0 = start; e0 < end; e0 += 64) {
            int e = e0 + lane;
            bool act = e < end;
            int idx = act ? esrc[e] : 0;
            float sc = -1e30f;
            if (act) {
                sc = ss[idx] + sd;
                sc = sc > 0.f ? sc : ALPHA * sc;
            }
            sidx = idx; ssc = sc;
            float mn = fmaxf(m, sc);
            s = s * __expf(m - mn) + (act ? __expf(sc - mn) : 0.f);
            m = mn;
        }
        float lm = m;
#pragma unroll
        for (int off = 1; off < 64; off <<= 1) m = fmaxf(m, __shfl_xor(m, off));
        float ptil = s * __expf(lm - m);
        s = ptil;
#pragma unroll
        for (int off = 1; off < 64; off <<= 1) s += __shfl_xor(s, off);
        float inv = 1.f / (s + GAT_EPS);

        int lastStart = start + (((end - start - 1) >> 6) << 6);
        for (int e0 = start; e0 < end; e0 += 64) {
            int e = e0 + lane;
            bool act = e < end;
            int idx; float p;
            if (e0 == lastStart) {
                idx = sidx;
                p = act ? __expf(ssc - m) * inv : 0.f;
            } else {
                idx = act ? esrc[e] : 0;
                float sc = -1e30f;
                if (act) {
                    sc = ss[idx] + sd;
                    sc = sc > 0.f ? sc : ALPHA * sc;
                }
                p = act ? __expf(sc - m) * inv : 0.f;
            }
            int cn = end - e0; if (cn > 64) cn = 64;
            if (lane < 62) {
                for (int j = 0; j < cn; j++) {
                    int ij = __builtin_amdgcn_readlane(idx, j);
                    float pj = rdlanef(p, j);
                    unsigned short w = *(const unsigned short*)(Wb + (size_t)ij * 768);
                    f32x2 f = cvt8<false>(w);
                    a0 += pj * f.x; a1 += pj * f.y;
                }
            }
        }
    }

    if (lane < 62) {
        part[h][2 * lane]     = a0;
        part[h][2 * lane + 1] = a1;
    }
    __syncthreads();
    if (t < 121) {
        float tot = (part[0][t] + part[1][t] + part[2][t] +
                     part[3][t] + part[4][t] + part[5][t]) * (1.f / 6.f);
        out[(size_t)n * 121 + t] = 1.f / (1.f + __expf(-tot));
    }
}

extern "C" void kernel_launch(void* const* d_in, const int* in_sizes, int n_in,
                              void* d_out, int out_size, void* d_ws, size_t ws_size,
                              hipStream_t stream) {
    const float* x  = (const float*)d_in[0];
    const int*   ei = (const int*)d_in[1];
    const float* W1 = (const float*)d_in[2];
    const float* a1 = (const float*)d_in[3];
    const float* W2 = (const float*)d_in[4];
    const float* a2 = (const float*)d_in[5];
    const float* W3 = (const float*)d_in[6];
    const float* a3 = (const float*)d_in[7];
    float* out = (float*)d_out;
    const int N = N_NODES, E = N_EDGES;
    const int* src = ei;
    const int* dst = ei + E;

    char* ws = (char*)d_ws;
    size_t off = 0;
    auto alloc = [&](size_t b) { size_t o = off; off += (b + 255) & ~(size_t)255; return o; };
    _Float16* X16  = (_Float16*)(ws + alloc((size_t)MPAD * 1024 * 2));  // x1 then x2 (fp16)
    unsigned char* WH8 = (unsigned char*)(ws + alloc((size_t)MPAD * 1024)); // per-layer Wh (fp8)
    _Float16* BT16 = (_Float16*)(ws + alloc((size_t)BT_ROWS * 1024 * 2));
    _Float16* A1   = (_Float16*)(ws + alloc((size_t)MPAD * 64 * 2));
    _Float16* BT1  = (_Float16*)(ws + alloc((size_t)BT_ROWS * 64 * 2));
    _Float16* XB   = (_Float16*)(ws + alloc((size_t)MPAD * 256 * 2));  // layer-1 xbar
    _Float16* BTS  = (_Float16*)(ws + alloc((size_t)128 * 64 * 2));    // layer-1 score cols
    float* SPRE   = (float*)(ws + alloc((size_t)12 * N * 4));
    int*   rowptr = (int*)(ws + alloc((size_t)(N + 1) * 4));
    int*   cursor = (int*)(ws + alloc((size_t)N * 4));
    int*   counts = (int*)(ws + alloc((size_t)N * 4));
    int*   excl   = (int*)(ws + alloc((size_t)N * 4));
    int*   partial= (int*)(ws + alloc((size_t)SCAN_BLKS * 4));
    int*   esrc   = (int*)(ws + alloc((size_t)E * 4));

    // CSR by dst
    hipMemsetAsync(counts, 0, (size_t)N * 4, stream);
    hist_kernel<<<(E + 255) / 256, 256, 0, stream>>>(dst, counts, E);
    scan1_kernel<<<SCAN_BLKS, 256, 0, stream>>>(counts, excl, partial, N);
    scan2_kernel<<<1, 128, 0, stream>>>(partial);
    scan3_kernel<<<SCAN_BLKS, 256, 0, stream>>>(excl, partial, rowptr, cursor, N, E);
    scatter_kernel<<<(E + 255) / 256, 256, 0, stream>>>(src, dst, cursor, esrc, E);
    hipMemsetAsync(X16 + (size_t)N * 1024, 0, (size_t)(MPAD - N) * 1024 * 2, stream);
    hipMemsetAsync(XB + (size_t)N * 256, 0, (size_t)(MPAD - N) * 256 * 2, stream);

    // ---- layer 1: scores from x@Wtil; aggregate x (L2-resident); block-diag GEMM ----
    pack_x16<<<MPAD * 64 / 256, 256, 0, stream>>>(x, A1);
    pack_bt1<<<1024 * 64 / 256, 256, 0, stream>>>(W1, BT1);
    wtilde_kernel<<<dim3(64, 8), 64, 0, stream>>>(W1, a1, BTS, 50, 64, 256, 4, 0);
    gemm_f16<<<8 * RHI * 1, 256, 0, stream>>>(A1, BTS, WH8, SPRE, N, 0, 1024, 64, 1, 64, 0);
    aggx1_kernel<<<N, 256, 0, stream>>>(rowptr, esrc, SPRE, A1, XB, N);
    gemm_f16<<<8 * RHI * 8, 256, 0, stream>>>(XB, BT1, (unsigned char*)X16, SPRE, N, 1024, 1024, 64, 8, 256, 1);

    // ---- layer 2: 1024 -> 4x256 concat + skip ----
    pack_bt16<<<dim3(4, 1024), 256, 0, stream>>>(W2, BT16, 256, 256, 1024);
    wtilde_kernel<<<dim3(1024, 8), 64, 0, stream>>>(W2, a2, BT16, 1024, 1024, 256, 4, 1024);
    gemm_f16<<<8 * RHI * 9, 256, 0, stream>>>(X16, BT16, WH8, SPRE, N, 1024, 1024, 1024, 9, 1024, 0);
    attagg256_kernel<<<N, 256, 0, stream>>>(rowptr, esrc, SPRE, WH8, X16, 1, N);

    // ---- layer 3: 1024 -> 6x121 (stride 124, zero-padded), mean + sigmoid ----
    pack_bt16<<<dim3(4, 744), 256, 0, stream>>>(W3, BT16, 121, 124, 744);
    wtilde_kernel<<<dim3(1024, 12), 64, 0, stream>>>(W3, a3, BT16, 1024, 1024, 121, 6, 744);
    gemm_f16<<<8 * RHI * 6, 256, 0, stream>>>(X16, BT16, WH8, SPRE, N, 744, 768, 1024, 6, 1024, 0);
    attagg726_kernel<<<N, 384, 0, stream>>>(rowptr, esrc, SPRE, WH8, out, N);
}

// Round 12
// 408.583 us; speedup vs baseline: 1.1172x; 1.0381x over previous
//
#include <hip/hip_runtime.h>
#include <cstdint>

#define N_NODES 20000
#define N_EDGES 320000
#define ALPHA 0.2f
#define GAT_EPS 1e-16f
#define MPAD 20096           // 157 * 128
#define RBLK 157
#define RHI 20               // ceil(157/8)
#define SCAN_BLKS 80
#define BT_ROWS 1152         // 9 col-blocks * 128

typedef __attribute__((ext_vector_type(8))) _Float16 half8;
typedef __attribute__((ext_vector_type(4))) _Float16 half4t;
typedef __attribute__((ext_vector_type(16))) float f32x16;
typedef __attribute__((ext_vector_type(2))) float f32x2;

__device__ __forceinline__ float elu1(float x) { return x > 0.f ? x : __expf(x) - 1.f; }

__device__ __forceinline__ unsigned char f2fp8(float x) {
    return (unsigned char)(__builtin_amdgcn_cvt_pk_fp8_f32(x, 0.f, 0, false) & 0xff);
}

__device__ __forceinline__ void async16(const void* g, void* l) {
    __builtin_amdgcn_global_load_lds(
        (const __attribute__((address_space(1))) unsigned int*)g,
        (__attribute__((address_space(3))) unsigned int*)l, 16, 0, 0);
}

__device__ __forceinline__ float rdlanef(float v, int j) {
    return __int_as_float(__builtin_amdgcn_readlane(__float_as_int(v), j));
}

template <bool HI>
__device__ __forceinline__ f32x2 cvt8(unsigned int u) {
    return __builtin_amdgcn_cvt_pk_f32_fp8((int)u, HI);
}

// ---------------- CSR build ----------------
__global__ void hist_kernel(const int* __restrict__ dst, int* __restrict__ counts, int E) {
    int e = blockIdx.x * blockDim.x + threadIdx.x;
    if (e < E) atomicAdd(&counts[dst[e]], 1);
}

__global__ void scan1_kernel(const int* __restrict__ counts, int* __restrict__ excl,
                             int* __restrict__ partial, int N) {
    __shared__ int sh[256];
    int t = threadIdx.x, b = blockIdx.x;
    int i = b * 256 + t;
    int v = (i < N) ? counts[i] : 0;
    sh[t] = v;
    __syncthreads();
    for (int d = 1; d < 256; d <<= 1) {
        int x = (t >= d) ? sh[t - d] : 0;
        __syncthreads();
        sh[t] += x;
        __syncthreads();
    }
    if (i < N) excl[i] = sh[t] - v;
    if (t == 255) partial[b] = sh[255];
}

__global__ void scan2_kernel(int* __restrict__ partial) {
    __shared__ int sh[128];
    int t = threadIdx.x;
    int v = (t < SCAN_BLKS) ? partial[t] : 0;
    sh[t] = v;
    __syncthreads();
    for (int d = 1; d < 128; d <<= 1) {
        int x = (t >= d) ? sh[t - d] : 0;
        __syncthreads();
        sh[t] += x;
        __syncthreads();
    }
    if (t < SCAN_BLKS) partial[t] = sh[t] - v;
}

__global__ void scan3_kernel(const int* __restrict__ excl, const int* __restrict__ partial,
                             int* __restrict__ rowptr, int* __restrict__ cursor, int N, int E) {
    int t = threadIdx.x, b = blockIdx.x;
    int i = b * 256 + t;
    if (i < N) {
        int v = excl[i] + partial[b];
        rowptr[i] = v;
        cursor[i] = v;
    }
    if (i == 0) rowptr[N] = E;
}

__global__ void scatter_kernel(const int* __restrict__ src, const int* __restrict__ dst,
                               int* __restrict__ cursor, int* __restrict__ esrc, int E) {
    int e = blockIdx.x * blockDim.x + threadIdx.x;
    if (e < E) {
        int p = atomicAdd(&cursor[dst[e]], 1);
        esrc[p] = src[e];
    }
}

// ---------------- packs ----------------
__global__ void pack_x16(const float* __restrict__ x, _Float16* __restrict__ A) {
    int idx = blockIdx.x * 256 + threadIdx.x;   // MPAD*64
    int r = idx >> 6, c = idx & 63;
    float v = (r < N_NODES && c < 50) ? x[r * 50 + c] : 0.f;
    A[idx] = (_Float16)v;
}

__global__ void pack_bt1(const float* __restrict__ W, _Float16* __restrict__ Bt) {
    int idx = blockIdx.x * 256 + threadIdx.x;   // 1024*64
    int c = idx >> 6, k = idx & 63;
    int h = c >> 8, f = c & 255;
    float v = (k < 50) ? W[((size_t)h * 50 + k) * 256 + f] : 0.f;
    Bt[idx] = (_Float16)v;
}

// generic: BT row c -> head h=c/Fpad, col f=c%Fpad; zero for f>=F (alignment pad)
__global__ void pack_bt16(const float* __restrict__ W, _Float16* __restrict__ Bt,
                          int F, int Fpad, int Ctot) {
    int c = blockIdx.y;
    int k = blockIdx.x * blockDim.x + threadIdx.x;
    float v = 0.f;
    if (c < Ctot) {
        int h = c / Fpad, f = c - h * Fpad;
        if (f < F) v = W[(size_t)h * 1024 * F + (size_t)k * F + f];
    }
    Bt[(size_t)c * 1024 + k] = (_Float16)v;
}

// W~ cols appended at BT rows [Nfeat, Nfeat+2H); gridDim.y MUST be 2*H.
__global__ __launch_bounds__(64) void wtilde_kernel(const float* __restrict__ W,
                                                    const float* __restrict__ a,
                                                    _Float16* __restrict__ BT, int Kreal,
                                                    int Kdim, int F, int H, int Nfeat) {
    int k = blockIdx.x, j = blockIdx.y;
    if (j >= 2 * H) return;
    int lane = threadIdx.x;
    int h = j < H ? j : j - H;
    int ao = j < H ? 0 : F;
    float s = 0.f;
    if (k < Kreal) {
        const float* wp = W + ((size_t)h * Kreal + k) * F;
        const float* ap = a + (size_t)h * 2 * F + ao;
        for (int f = lane; f < F; f += 64) s += wp[f] * ap[f];
    }
#pragma unroll
    for (int off = 32; off; off >>= 1) s += __shfl_down(s, off);
    if (lane == 0) BT[(size_t)(Nfeat + j) * Kdim + k] = (_Float16)s;
}

// ---------------- fp16 MFMA GEMM (32x32x16) ----------------
__global__ __launch_bounds__(256) void gemm_f16(const _Float16* __restrict__ A,
                                                const _Float16* __restrict__ BT,
                                                unsigned char* __restrict__ C8,
                                                float* __restrict__ SPRE,
                                                int M, int Nfeat, int ld, int Kdim, int Cblk,
                                                int ldA, int mode) {
    int id = blockIdx.x;
    int xm = id & 7, q = id >> 3;
    int cb = q % Cblk, rh = q / Cblk;
    int rb = rh * 8 + xm;
    if (rb >= RBLK) return;
    __shared__ __align__(16) _Float16 sA[128 * 64];
    __shared__ __align__(16) _Float16 sB[128 * 64];
    int t = threadIdx.x;
    int row0 = rb * 128, col0 = cb * 128;
    int lane = t & 63, wave = t >> 6;
    int wm = wave >> 1, wn = wave & 1;
    int l31 = lane & 31;
    int lhi = lane >> 5;

    int koff = (mode == 1) ? ((cb >> 1) * 64) : 0;
    const _Float16* gA = A + (size_t)row0 * ldA + koff;
    const _Float16* gB = BT + (size_t)col0 * Kdim;

    int sR[4], sgl[4];
#pragma unroll
    for (int i = 0; i < 4; i++) {
        int m = i * 256 + t;
        sR[i] = m >> 3;
        sgl[i] = (m & 7) ^ (sR[i] & 7);
    }

    f32x16 acc[2][2] = {};

    for (int k0 = 0; k0 < Kdim; k0 += 64) {
        __syncthreads();
#pragma unroll
        for (int i = 0; i < 4; i++) {
            const _Float16* pa = gA + (size_t)sR[i] * ldA + k0 + sgl[i] * 8;
            const _Float16* pb = gB + (size_t)sR[i] * Kdim + k0 + sgl[i] * 8;
            async16(pa, sA + (i * 256 + t) * 8);
            async16(pb, sB + (i * 256 + t) * 8);
        }
        __syncthreads();
#pragma unroll
        for (int kk = 0; kk < 4; kk++) {
            int g = kk * 2 + lhi;
            half8 af[2], bf[2];
#pragma unroll
            for (int mt = 0; mt < 2; mt++) {
                int R = wm * 64 + mt * 32 + l31;
                int gp = g ^ (R & 7);
                af[mt] = *(const half8*)(sA + R * 64 + gp * 8);
            }
#pragma unroll
            for (int nt = 0; nt < 2; nt++) {
                int R = wn * 64 + nt * 32 + l31;
                int gp = g ^ (R & 7);
                bf[nt] = *(const half8*)(sB + R * 64 + gp * 8);
            }
#pragma unroll
            for (int mt = 0; mt < 2; mt++)
#pragma unroll
                for (int nt = 0; nt < 2; nt++)
                    acc[mt][nt] = __builtin_amdgcn_mfma_f32_32x32x16_f16(af[mt], bf[nt], acc[mt][nt], 0, 0, 0);
        }
    }

    int cb32 = col0 + wn * 64 + l31;
    int rb32 = row0 + wm * 64 + 4 * lhi;
    if (mode == 1) {
        _Float16* C16 = (_Float16*)C8;
#pragma unroll
        for (int mt = 0; mt < 2; mt++)
#pragma unroll
            for (int nt = 0; nt < 2; nt++) {
                int gc = cb32 + nt * 32;
                if (gc < Nfeat) {
#pragma unroll
                    for (int r = 0; r < 16; r++) {
                        int gr = rb32 + mt * 32 + (r & 3) + 8 * (r >> 2);
                        if (gr < M) C16[(size_t)gr * ld + gc] = (_Float16)elu1(elu1(acc[mt][nt][r]));
                    }
                }
            }
        return;
    }
#pragma unroll
    for (int mt = 0; mt < 2; mt++)
#pragma unroll
        for (int nt = 0; nt < 2; nt++) {
            int gc = cb32 + nt * 32;
            if (gc < Nfeat) {
#pragma unroll
                for (int r = 0; r < 16; r++) {
                    int gr = rb32 + mt * 32 + (r & 3) + 8 * (r >> 2);
                    if (gr < M) C8[(size_t)gr * ld + gc] = f2fp8(acc[mt][nt][r]);
                }
            } else if (gc < Nfeat + 12) {
                int j = gc - Nfeat;
#pragma unroll
                for (int r = 0; r < 16; r++) {
                    int gr = rb32 + mt * 32 + (r & 3) + 8 * (r >> 2);
                    if (gr < M) SPRE[(size_t)j * N_NODES + gr] = acc[mt][nt][r];
                }
            }
        }
}

// ---------------- layer 1: ONE wave per node serves ALL 4 heads ----------------
// x-row (128B fp16) fits one wave exactly (lane = feature col), so the old 4-wave
// version gathered each row 4x redundantly. Now: per edge 1 gather + 4 readlane +
// 4 FMA; 4 softmax reduces interleaved in one shuffle loop (same 12-step depth).
// Scores for all heads gathered from L2-resident SPRE.
__global__ __launch_bounds__(256) void aggx1_kernel(const int* __restrict__ rowptr,
                                                    const int* __restrict__ esrc,
                                                    const float* __restrict__ SPRE,
                                                    const _Float16* __restrict__ A1,
                                                    _Float16* __restrict__ XB, int N) {
    int wv = threadIdx.x >> 6;
    int lane = threadIdx.x & 63;
    int n = blockIdx.x * 4 + wv;
    if (n >= N) return;
    int start = rowptr[n], end = rowptr[n + 1];
    int cnt = end - start;
    float sd0 = SPRE[(size_t)4 * N + n];
    float sd1 = SPRE[(size_t)5 * N + n];
    float sd2 = SPRE[(size_t)6 * N + n];
    float sd3 = SPRE[(size_t)7 * N + n];
    const unsigned char* Wb = (const unsigned char*)A1 + 2 * lane;
    float acc0 = 0.f, acc1 = 0.f, acc2 = 0.f, acc3 = 0.f;

    if (cnt <= 64) {
        int e = start + lane;
        bool act = e < end;
        int idx = act ? esrc[e] : 0;
        // early score gathers for all 4 heads (L2-resident SPRE)
        float g0 = SPRE[idx];
        float g1 = SPRE[(size_t)N + idx];
        float g2 = SPRE[(size_t)2 * N + idx];
        float g3 = SPRE[(size_t)3 * N + idx];
        int voff = idx << 7;

        unsigned short wA[8], wB[8], wC[8], wD[8];
        auto ISSUE = [&](unsigned short (&buf)[8], int base) {
#pragma unroll
            for (int u = 0; u < 8; u++) {
                int off = __builtin_amdgcn_readlane(voff, base + u);
                buf[u] = *(const unsigned short*)(Wb + (unsigned)off);
            }
        };
        ISSUE(wA, 0);
        if (cnt > 8)  ISSUE(wB, 8);
        if (cnt > 16) ISSUE(wC, 16);
        if (cnt > 24) ISSUE(wD, 24);

        float sc0 = -1e30f, sc1 = -1e30f, sc2 = -1e30f, sc3 = -1e30f;
        if (act) {
            sc0 = g0 + sd0; sc0 = sc0 > 0.f ? sc0 : ALPHA * sc0;
            sc1 = g1 + sd1; sc1 = sc1 > 0.f ? sc1 : ALPHA * sc1;
            sc2 = g2 + sd2; sc2 = sc2 > 0.f ? sc2 : ALPHA * sc2;
            sc3 = g3 + sd3; sc3 = sc3 > 0.f ? sc3 : ALPHA * sc3;
        }
        float m0 = sc0, m1 = sc1, m2 = sc2, m3 = sc3;
#pragma unroll
        for (int off = 1; off < 64; off <<= 1) {
            m0 = fmaxf(m0, __shfl_xor(m0, off));
            m1 = fmaxf(m1, __shfl_xor(m1, off));
            m2 = fmaxf(m2, __shfl_xor(m2, off));
            m3 = fmaxf(m3, __shfl_xor(m3, off));
        }
        float p0 = act ? __expf(sc0 - m0) : 0.f;
        float p1 = act ? __expf(sc1 - m1) : 0.f;
        float p2 = act ? __expf(sc2 - m2) : 0.f;
        float p3 = act ? __expf(sc3 - m3) : 0.f;
        float s0 = p0, s1 = p1, s2 = p2, s3 = p3;
#pragma unroll
        for (int off = 1; off < 64; off <<= 1) {
            s0 += __shfl_xor(s0, off);
            s1 += __shfl_xor(s1, off);
            s2 += __shfl_xor(s2, off);
            s3 += __shfl_xor(s3, off);
        }
        p0 *= 1.f / (s0 + GAT_EPS);
        p1 *= 1.f / (s1 + GAT_EPS);
        p2 *= 1.f / (s2 + GAT_EPS);
        p3 *= 1.f / (s3 + GAT_EPS);

        auto CONSUME = [&](unsigned short (&buf)[8], int base) {
#pragma unroll
            for (int u = 0; u < 8; u++) {
                float xv = (float)(*(const _Float16*)&buf[u]);
                acc0 += rdlanef(p0, base + u) * xv;
                acc1 += rdlanef(p1, base + u) * xv;
                acc2 += rdlanef(p2, base + u) * xv;
                acc3 += rdlanef(p3, base + u) * xv;
            }
        };
        __builtin_amdgcn_s_setprio(1);
        CONSUME(wA, 0);
        if (cnt > 8)  { if (cnt > 32) ISSUE(wA, 32); CONSUME(wB, 8); }
        if (cnt > 16) { if (cnt > 40) ISSUE(wB, 40); CONSUME(wC, 16); }
        if (cnt > 24) { if (cnt > 48) ISSUE(wC, 48); CONSUME(wD, 24); }
        if (cnt > 32) { if (cnt > 56) ISSUE(wD, 56); CONSUME(wA, 32); }
        if (cnt > 40) CONSUME(wB, 40);
        if (cnt > 48) CONSUME(wC, 48);
        if (cnt > 56) CONSUME(wD, 56);
        __builtin_amdgcn_s_setprio(0);
    } else {
        // fallback (deg > 64, vanishingly rare): per-head chunked passes
#pragma unroll
        for (int h = 0; h < 4; h++) {
            const float* ss = SPRE + (size_t)h * N;
            float sd = SPRE[(size_t)(4 + h) * N + n];
            float m = -1e30f, s = 0.f;
            for (int e0 = start; e0 < end; e0 += 64) {
                int e = e0 + lane;
                bool act = e < end;
                int idx = act ? esrc[e] : 0;
                float sc = -1e30f;
                if (act) {
                    sc = ss[idx] + sd;
                    sc = sc > 0.f ? sc : ALPHA * sc;
                }
                float mn = fmaxf(m, sc);
                s = s * __expf(m - mn) + (act ? __expf(sc - mn) : 0.f);
                m = mn;
            }
            float lm = m;
#pragma unroll
            for (int off = 1; off < 64; off <<= 1) m = fmaxf(m, __shfl_xor(m, off));
            float ptil = s * __expf(lm - m);
            s = ptil;
#pragma unroll
            for (int off = 1; off < 64; off <<= 1) s += __shfl_xor(s, off);
            float inv = 1.f / (s + GAT_EPS);
            float acch = 0.f;
            for (int e0 = start; e0 < end; e0 += 64) {
                int e = e0 + lane;
                bool act = e < end;
                int idx = act ? esrc[e] : 0;
                float sc = -1e30f;
                if (act) {
                    sc = ss[idx] + sd;
                    sc = sc > 0.f ? sc : ALPHA * sc;
                }
                float p = act ? __expf(sc - m) * inv : 0.f;
                int cn = end - e0; if (cn > 64) cn = 64;
                for (int j = 0; j < cn; j++) {
                    int ij = __builtin_amdgcn_readlane(idx, j);
                    float pj = rdlanef(p, j);
                    unsigned short w = *(const unsigned short*)(Wb + ((size_t)(unsigned)ij << 7));
                    acch += pj * (float)(*(const _Float16*)&w);
                }
            }
            if (h == 0) acc0 = acch;
            else if (h == 1) acc1 = acch;
            else if (h == 2) acc2 = acch;
            else acc3 = acch;
        }
    }

    size_t ob = (size_t)n * 256 + lane;
    XB[ob]       = (_Float16)acc0;
    XB[ob + 64]  = (_Float16)acc1;
    XB[ob + 128] = (_Float16)acc2;
    XB[ob + 192] = (_Float16)acc3;
}

// ---------------- layer 2 att+agg (fused broadcast 4-deep, r11 best) ----------
__global__ __launch_bounds__(256) void attagg256_kernel(const int* __restrict__ rowptr,
                                                        const int* __restrict__ esrc,
                                                        const float* __restrict__ SPRE,
                                                        const unsigned char* __restrict__ WH8,
                                                        _Float16* __restrict__ X16,
                                                        int use_skip, int N) {
    int n = blockIdx.x;
    int h = threadIdx.x >> 6;
    int lane = threadIdx.x & 63;
    int start = rowptr[n], end = rowptr[n + 1];
    int cnt = end - start;
    const float* ss = SPRE + (size_t)h * N;
    float sd = SPRE[(size_t)(4 + h) * N + n];
    const unsigned char* Wb = WH8 + h * 256 + lane * 4;
    size_t o = (size_t)n * 1024 + h * 256 + lane * 4;
    half4t sk = {};
    if (use_skip) sk = *(const half4t*)(X16 + o);   // prefetch skip (hides ~600cy)
    float a0 = 0.f, a1 = 0.f, a2 = 0.f, a3 = 0.f;

    if (cnt <= 64) {
        int e = start + lane;
        bool act = e < end;
        int idx = act ? esrc[e] : 0;
        float sv = ss[idx];              // early score gather

        unsigned int wA[8], wB[8], wC[8], wD[8];
        auto ISSUE = [&](unsigned int (&buf)[8], int base) {
#pragma unroll
            for (int u = 0; u < 8; u++) {
                int ij = __builtin_amdgcn_readlane(idx, base + u);
                buf[u] = *(const unsigned int*)(Wb + ((size_t)(unsigned)ij << 10));
            }
        };
        ISSUE(wA, 0);
        if (cnt > 8)  ISSUE(wB, 8);
        if (cnt > 16) ISSUE(wC, 16);
        if (cnt > 24) ISSUE(wD, 24);

        float sc = -1e30f;
        if (act) {
            sc = sv + sd;
            sc = sc > 0.f ? sc : ALPHA * sc;
        }
        float m = sc;
#pragma unroll
        for (int off = 1; off < 64; off <<= 1) m = fmaxf(m, __shfl_xor(m, off));
        float ptil = act ? __expf(sc - m) : 0.f;
        float s = ptil;
#pragma unroll
        for (int off = 1; off < 64; off <<= 1) s += __shfl_xor(s, off);
        float p = ptil * (1.f / (s + GAT_EPS));

        auto CONSUME = [&](unsigned int (&buf)[8], int base) {
#pragma unroll
            for (int u = 0; u < 8; u++) {
                float pj = rdlanef(p, base + u);
                f32x2 lo = cvt8<false>(buf[u]);
                f32x2 hi = cvt8<true>(buf[u]);
                a0 += pj * lo.x; a1 += pj * lo.y; a2 += pj * hi.x; a3 += pj * hi.y;
            }
        };
        __builtin_amdgcn_s_setprio(1);
        CONSUME(wA, 0);
        if (cnt > 8)  { if (cnt > 32) ISSUE(wA, 32); CONSUME(wB, 8); }
        if (cnt > 16) { if (cnt > 40) ISSUE(wB, 40); CONSUME(wC, 16); }
        if (cnt > 24) { if (cnt > 48) ISSUE(wC, 48); CONSUME(wD, 24); }
        if (cnt > 32) { if (cnt > 56) ISSUE(wD, 56); CONSUME(wA, 32); }
        if (cnt > 40) CONSUME(wB, 40);
        if (cnt > 48) CONSUME(wC, 48);
        if (cnt > 56) CONSUME(wD, 56);
        __builtin_amdgcn_s_setprio(0);
    } else {
        float m = -1e30f, s = 0.f;
        int sidx = 0; float ssc = -1e30f;
        for (int e0 = start; e0 < end; e0 += 64) {
            int e = e0 + lane;
            bool act = e < end;
            int idx = act ? esrc[e] : 0;
            float sc = -1e30f;
            if (act) {
                sc = ss[idx] + sd;
                sc = sc > 0.f ? sc : ALPHA * sc;
            }
            sidx = idx; ssc = sc;
            float mn = fmaxf(m, sc);
            s = s * __expf(m - mn) + (act ? __expf(sc - mn) : 0.f);
            m = mn;
        }
        float lm = m;
#pragma unroll
        for (int off = 1; off < 64; off <<= 1) m = fmaxf(m, __shfl_xor(m, off));
        float ptil = s * __expf(lm - m);
        s = ptil;
#pragma unroll
        for (int off = 1; off < 64; off <<= 1) s += __shfl_xor(s, off);
        float inv = 1.f / (s + GAT_EPS);

        int lastStart = start + (((end - start - 1) >> 6) << 6);
        for (int e0 = start; e0 < end; e0 += 64) {
            int e = e0 + lane;
            bool act = e < end;
            int idx; float p;
            if (e0 == lastStart) {
                idx = sidx;
                p = act ? __expf(ssc - m) * inv : 0.f;
            } else {
                idx = act ? esrc[e] : 0;
                float sc = -1e30f;
                if (act) {
                    sc = ss[idx] + sd;
                    sc = sc > 0.f ? sc : ALPHA * sc;
                }
                p = act ? __expf(sc - m) * inv : 0.f;
            }
            int cn = end - e0; if (cn > 64) cn = 64;
            for (int j = 0; j < cn; j++) {
                int ij = __builtin_amdgcn_readlane(idx, j);
                float pj = rdlanef(p, j);
                unsigned int w = *(const unsigned int*)(Wb + (size_t)ij * 1024);
                f32x2 lo = cvt8<false>(w);
                f32x2 hi = cvt8<true>(w);
                a0 += pj * lo.x; a1 += pj * lo.y; a2 += pj * hi.x; a3 += pj * hi.y;
            }
        }
    }

    float v0, v1, v2, v3;
    if (use_skip) {
        v0 = elu1(elu1(a0) + (float)sk.x);
        v1 = elu1(elu1(a1) + (float)sk.y);
        v2 = elu1(elu1(a2) + (float)sk.z);
        v3 = elu1(elu1(a3) + (float)sk.w);
    } else {
        v0 = elu1(elu1(a0)); v1 = elu1(elu1(a1));
        v2 = elu1(elu1(a2)); v3 = elu1(elu1(a3));
    }
    half4t r;
    r.x = (_Float16)v0; r.y = (_Float16)v1; r.z = (_Float16)v2; r.w = (_Float16)v3;
    *(half4t*)(X16 + o) = r;
}

// ---------------- layer 3 att+agg (broadcast 4-deep, known-best) ----------
__global__ __launch_bounds__(384) void attagg726_kernel(const int* __restrict__ rowptr,
                                                        const int* __restrict__ esrc,
                                                        const float* __restrict__ SPRE,
                                                        const unsigned char* __restrict__ WH8,
                                                        float* __restrict__ out, int N) {
    __shared__ float part[6][124];
    int n = blockIdx.x;
    int t = threadIdx.x;
    int h = t >> 6;
    int lane = t & 63;
    int start = rowptr[n], end = rowptr[n + 1];
    int cnt = end - start;
    const float* ss = SPRE + (size_t)h * N;
    float sd = SPRE[(size_t)(6 + h) * N + n];
    const unsigned char* Wb = WH8 + h * 124 + 2 * lane;
    float a0 = 0.f, a1 = 0.f;

    if (cnt <= 64) {
        int e = start + lane;
        bool act = e < end;
        int idx = act ? esrc[e] : 0;
        float sv = ss[idx];              // early score gather

        unsigned short wA[8], wB[8], wC[8], wD[8];
        auto ISSUE = [&](unsigned short (&buf)[8], int base) {
#pragma unroll
            for (int u = 0; u < 8; u++) {
                int ij = __builtin_amdgcn_readlane(idx, base + u);
                buf[u] = *(const unsigned short*)(Wb + (size_t)(unsigned)ij * 768u);
            }
        };
        ISSUE(wA, 0);
        if (cnt > 8)  ISSUE(wB, 8);
        if (cnt > 16) ISSUE(wC, 16);
        if (cnt > 24) ISSUE(wD, 24);

        float sc = -1e30f;
        if (act) {
            sc = sv + sd;
            sc = sc > 0.f ? sc : ALPHA * sc;
        }
        float m = sc;
#pragma unroll
        for (int off = 1; off < 64; off <<= 1) m = fmaxf(m, __shfl_xor(m, off));
        float ptil = act ? __expf(sc - m) : 0.f;
        float s = ptil;
#pragma unroll
        for (int off = 1; off < 64; off <<= 1) s += __shfl_xor(s, off);
        float p = ptil * (1.f / (s + GAT_EPS));

        auto CONSUME = [&](unsigned short (&buf)[8], int base) {
#pragma unroll
            for (int u = 0; u < 8; u++) {
                float pj = rdlanef(p, base + u);
                f32x2 f = cvt8<false>(buf[u]);
                a0 += pj * f.x; a1 += pj * f.y;
            }
        };
        __builtin_amdgcn_s_setprio(1);
        CONSUME(wA, 0);
        if (cnt > 8)  { if (cnt > 32) ISSUE(wA, 32); CONSUME(wB, 8); }
        if (cnt > 16) { if (cnt > 40) ISSUE(wB, 40); CONSUME(wC, 16); }
        if (cnt > 24) { if (cnt > 48) ISSUE(wC, 48); CONSUME(wD, 24); }
        if (cnt > 32) { if (cnt > 56) ISSUE(wD, 56); CONSUME(wA, 32); }
        if (cnt > 40) CONSUME(wB, 40);
        if (cnt > 48) CONSUME(wC, 48);
        if (cnt > 56) CONSUME(wD, 56);
        __builtin_amdgcn_s_setprio(0);
    } else {
        float m = -1e30f, s = 0.f;
        int sidx = 0; float ssc = -1e30f;
        for (int e0 = start; e0 < end; e0 += 64) {
            int e = e0 + lane;
            bool act = e < end;
            int idx = act ? esrc[e] : 0;
            float sc = -1e30f;
            if (act) {
                sc = ss[idx] + sd;
                sc = sc > 0.f ? sc : ALPHA * sc;
            }
            sidx = idx; ssc = sc;
            float mn = fmaxf(m, sc);
            s = s * __expf(m - mn) + (act ? __expf(sc - mn) : 0.f);
            m = mn;
        }
        float lm = m;
#pragma unroll
        for (int off = 1; off < 64; off <<= 1) m = fmaxf(m, __shfl_xor(m, off));
        float ptil = s * __expf(lm - m);
        s = ptil;
#pragma unroll
        for (int off = 1; off < 64; off <<= 1) s += __shfl_xor(s, off);
        float inv = 1.f / (s + GAT_EPS);

        int lastStart = start + (((end - start - 1) >> 6) << 6);
        for (int e0 = start; e0 < end; e0 += 64) {
            int e = e0 + lane;
            bool act = e < end;
            int idx; float p;
            if (e0 == lastStart) {
                idx = sidx;
                p = act ? __expf(ssc - m) * inv : 0.f;
            } else {
                idx = act ? esrc[e] : 0;
                float sc = -1e30f;
                if (act) {
                    sc = ss[idx] + sd;
                    sc = sc > 0.f ? sc : ALPHA * sc;
                }
                p = act ? __expf(sc - m) * inv : 0.f;
            }
            int cn = end - e0; if (cn > 64) cn = 64;
            if (lane < 62) {
                for (int j = 0; j < cn; j++) {
                    int ij = __builtin_amdgcn_readlane(idx, j);
                    float pj = rdlanef(p, j);
                    unsigned short w = *(const unsigned short*)(Wb + (size_t)ij * 768);
                    f32x2 f = cvt8<false>(w);
                    a0 += pj * f.x; a1 += pj * f.y;
                }
            }
        }
    }

    if (lane < 62) {
        part[h][2 * lane]     = a0;
        part[h][2 * lane + 1] = a1;
    }
    __syncthreads();
    if (t < 121) {
        float tot = (part[0][t] + part[1][t] + part[2][t] +
                     part[3][t] + part[4][t] + part[5][t]) * (1.f / 6.f);
        out[(size_t)n * 121 + t] = 1.f / (1.f + __expf(-tot));
    }
}

extern "C" void kernel_launch(void* const* d_in, const int* in_sizes, int n_in,
                              void* d_out, int out_size, void* d_ws, size_t ws_size,
                              hipStream_t stream) {
    const float* x  = (const float*)d_in[0];
    const int*   ei = (const int*)d_in[1];
    const float* W1 = (const float*)d_in[2];
    const float* a1 = (const float*)d_in[3];
    const float* W2 = (const float*)d_in[4];
    const float* a2 = (const float*)d_in[5];
    const float* W3 = (const float*)d_in[6];
    const float* a3 = (const float*)d_in[7];
    float* out = (float*)d_out;
    const int N = N_NODES, E = N_EDGES;
    const int* src = ei;
    const int* dst = ei + E;

    char* ws = (char*)d_ws;
    size_t off = 0;
    auto alloc = [&](size_t b) { size_t o = off; off += (b + 255) & ~(size_t)255; return o; };
    _Float16* X16  = (_Float16*)(ws + alloc((size_t)MPAD * 1024 * 2));  // x1 then x2 (fp16)
    unsigned char* WH8 = (unsigned char*)(ws + alloc((size_t)MPAD * 1024)); // per-layer Wh (fp8)
    _Float16* BT16 = (_Float16*)(ws + alloc((size_t)BT_ROWS * 1024 * 2));
    _Float16* A1   = (_Float16*)(ws + alloc((size_t)MPAD * 64 * 2));
    _Float16* BT1  = (_Float16*)(ws + alloc((size_t)BT_ROWS * 64 * 2));
    _Float16* XB   = (_Float16*)(ws + alloc((size_t)MPAD * 256 * 2));  // layer-1 xbar
    _Float16* BTS  = (_Float16*)(ws + alloc((size_t)128 * 64 * 2));    // layer-1 score cols
    float* SPRE   = (float*)(ws + alloc((size_t)12 * N * 4));
    int*   rowptr = (int*)(ws + alloc((size_t)(N + 1) * 4));
    int*   cursor = (int*)(ws + alloc((size_t)N * 4));
    int*   counts = (int*)(ws + alloc((size_t)N * 4));
    int*   excl   = (int*)(ws + alloc((size_t)N * 4));
    int*   partial= (int*)(ws + alloc((size_t)SCAN_BLKS * 4));
    int*   esrc   = (int*)(ws + alloc((size_t)E * 4));

    // CSR by dst
    hipMemsetAsync(counts, 0, (size_t)N * 4, stream);
    hist_kernel<<<(E + 255) / 256, 256, 0, stream>>>(dst, counts, E);
    scan1_kernel<<<SCAN_BLKS, 256, 0, stream>>>(counts, excl, partial, N);
    scan2_kernel<<<1, 128, 0, stream>>>(partial);
    scan3_kernel<<<SCAN_BLKS, 256, 0, stream>>>(excl, partial, rowptr, cursor, N, E);
    scatter_kernel<<<(E + 255) / 256, 256, 0, stream>>>(src, dst, cursor, esrc, E);
    hipMemsetAsync(X16 + (size_t)N * 1024, 0, (size_t)(MPAD - N) * 1024 * 2, stream);
    hipMemsetAsync(XB + (size_t)N * 256, 0, (size_t)(MPAD - N) * 256 * 2, stream);

    // ---- layer 1: scores from x@Wtil; aggregate x (L2-resident); block-diag GEMM ----
    pack_x16<<<MPAD * 64 / 256, 256, 0, stream>>>(x, A1);
    pack_bt1<<<1024 * 64 / 256, 256, 0, stream>>>(W1, BT1);
    wtilde_kernel<<<dim3(64, 8), 64, 0, stream>>>(W1, a1, BTS, 50, 64, 256, 4, 0);
    gemm_f16<<<8 * RHI * 1, 256, 0, stream>>>(A1, BTS, WH8, SPRE, N, 0, 1024, 64, 1, 64, 0);
    aggx1_kernel<<<(N + 3) / 4, 256, 0, stream>>>(rowptr, esrc, SPRE, A1, XB, N);
    gemm_f16<<<8 * RHI * 8, 256, 0, stream>>>(XB, BT1, (unsigned char*)X16, SPRE, N, 1024, 1024, 64, 8, 256, 1);

    // ---- layer 2: 1024 -> 4x256 concat + skip ----
    pack_bt16<<<dim3(4, 1024), 256, 0, stream>>>(W2, BT16, 256, 256, 1024);
    wtilde_kernel<<<dim3(1024, 8), 64, 0, stream>>>(W2, a2, BT16, 1024, 1024, 256, 4, 1024);
    gemm_f16<<<8 * RHI * 9, 256, 0, stream>>>(X16, BT16, WH8, SPRE, N, 1024, 1024, 1024, 9, 1024, 0);
    attagg256_kernel<<<N, 256, 0, stream>>>(rowptr, esrc, SPRE, WH8, X16, 1, N);

    // ---- layer 3: 1024 -> 6x121 (stride 124, zero-padded), mean + sigmoid ----
    pack_bt16<<<dim3(4, 744), 256, 0, stream>>>(W3, BT16, 121, 124, 744);
    wtilde_kernel<<<dim3(1024, 12), 64, 0, stream>>>(W3, a3, BT16, 1024, 1024, 121, 6, 744);
    gemm_f16<<<8 * RHI * 6, 256, 0, stream>>>(X16, BT16, WH8, SPRE, N, 744, 768, 1024, 6, 1024, 0);
    attagg726_kernel<<<N, 384, 0, stream>>>(rowptr, esrc, SPRE, WH8, out, N);
}

// Round 13
// 403.998 us; speedup vs baseline: 1.1299x; 1.0114x over previous
//
#include <hip/hip_runtime.h>
#include <cstdint>

#define N_NODES 20000
#define N_EDGES 320000
#define ALPHA 0.2f
#define GAT_EPS 1e-16f
#define MPAD 20096           // 157 * 128
#define RBLK 157
#define RHI 20               // ceil(157/8)
#define SCAN_BLKS 80
#define BT_ROWS 1152         // 9 col-blocks * 128

// fused-grid block counts
#define HB1 1250             // hist: E/256
#define PXB 5024             // pack_x16: MPAD*64/256
#define PB1 256              // pack_bt1: 1024*64/256
#define WT1B 128             // wtilde L1: 64*8 pairs / 4
#define AGB 5000             // aggx1: N/4
#define PL2 4096             // pack_bt16 L2: 4*1024
#define WT2B 2048            // wtilde L2: 1024*8 / 4
#define PL3 2976             // pack_bt16 L3: 4*744
#define WT3B 3072            // wtilde L3: 1024*12 / 4

typedef __attribute__((ext_vector_type(8))) _Float16 half8;
typedef __attribute__((ext_vector_type(4))) _Float16 half4t;
typedef __attribute__((ext_vector_type(16))) float f32x16;
typedef __attribute__((ext_vector_type(2))) float f32x2;

__device__ __forceinline__ float elu1(float x) { return x > 0.f ? x : __expf(x) - 1.f; }

__device__ __forceinline__ unsigned char f2fp8(float x) {
    return (unsigned char)(__builtin_amdgcn_cvt_pk_fp8_f32(x, 0.f, 0, false) & 0xff);
}

__device__ __forceinline__ void async16(const void* g, void* l) {
    __builtin_amdgcn_global_load_lds(
        (const __attribute__((address_space(1))) unsigned int*)g,
        (__attribute__((address_space(3))) unsigned int*)l, 16, 0, 0);
}

__device__ __forceinline__ float rdlanef(float v, int j) {
    return __int_as_float(__builtin_amdgcn_readlane(__float_as_int(v), j));
}

template <bool HI>
__device__ __forceinline__ f32x2 cvt8(unsigned int u) {
    return __builtin_amdgcn_cvt_pk_f32_fp8((int)u, HI);
}

// ---------------- shared device bodies ----------------
__device__ __forceinline__ void wtilde_pair(const float* __restrict__ W,
                                            const float* __restrict__ a,
                                            _Float16* __restrict__ BT,
                                            int Kreal, int Kdim, int F, int H, int Nfeat,
                                            int k, int j, int lane) {
    int h = j < H ? j : j - H;
    int ao = j < H ? 0 : F;
    float s = 0.f;
    if (k < Kreal) {
        const float* wp = W + ((size_t)h * Kreal + k) * F;
        const float* ap = a + (size_t)h * 2 * F + ao;
        for (int f = lane; f < F; f += 64) s += wp[f] * ap[f];
    }
#pragma unroll
    for (int off = 32; off; off >>= 1) s += __shfl_down(s, off);
    if (lane == 0) BT[(size_t)(Nfeat + j) * Kdim + k] = (_Float16)s;
}

__device__ __forceinline__ void pack_bt16_body(const float* __restrict__ W,
                                               _Float16* __restrict__ Bt,
                                               int F, int Fpad, int Ctot, int c, int k) {
    float v = 0.f;
    if (c < Ctot) {
        int h = c / Fpad, f = c - h * Fpad;
        if (f < F) v = W[(size_t)h * 1024 * F + (size_t)k * F + f];
    }
    Bt[(size_t)c * 1024 + k] = (_Float16)v;
}

// ---------------- CSR + layer-1 packs, fused grid ----------------
__global__ __launch_bounds__(256) void hist_plus(const int* __restrict__ dst,
                                                 int* __restrict__ counts, int E,
                                                 const float* __restrict__ x,
                                                 _Float16* __restrict__ A1,
                                                 const float* __restrict__ W1,
                                                 _Float16* __restrict__ BT1,
                                                 const float* __restrict__ a1,
                                                 _Float16* __restrict__ BTS) {
    int b = blockIdx.x, t = threadIdx.x;
    if (b < HB1) {
        int e = b * 256 + t;
        if (e < E) atomicAdd(&counts[dst[e]], 1);
    } else if (b < HB1 + PXB) {
        int idx = (b - HB1) * 256 + t;
        int r = idx >> 6, c = idx & 63;
        float v = (r < N_NODES && c < 50) ? x[r * 50 + c] : 0.f;
        A1[idx] = (_Float16)v;
    } else if (b < HB1 + PXB + PB1) {
        int idx = (b - HB1 - PXB) * 256 + t;
        int c = idx >> 6, k = idx & 63;
        int h = c >> 8, f = c & 255;
        float v = (k < 50) ? W1[((size_t)h * 50 + k) * 256 + f] : 0.f;
        BT1[idx] = (_Float16)v;
    } else {
        int p = (b - HB1 - PXB - PB1) * 4 + (t >> 6);
        wtilde_pair(W1, a1, BTS, 50, 64, 256, 4, 0, p & 63, p >> 6, t & 63);
    }
}

__global__ void scan1_kernel(const int* __restrict__ counts, int* __restrict__ excl,
                             int* __restrict__ partial, int N) {
    __shared__ int sh[256];
    int t = threadIdx.x, b = blockIdx.x;
    int i = b * 256 + t;
    int v = (i < N) ? counts[i] : 0;
    sh[t] = v;
    __syncthreads();
    for (int d = 1; d < 256; d <<= 1) {
        int x = (t >= d) ? sh[t - d] : 0;
        __syncthreads();
        sh[t] += x;
        __syncthreads();
    }
    if (i < N) excl[i] = sh[t] - v;
    if (t == 255) partial[b] = sh[255];
}

// scan3 with inline 80-entry prefix (absorbs old scan2): base_b = sum(partial[0..b))
__global__ void scan3_kernel(const int* __restrict__ excl, const int* __restrict__ partial,
                             int* __restrict__ rowptr, int* __restrict__ cursor, int N, int E) {
    __shared__ int wsum[4];
    int t = threadIdx.x, b = blockIdx.x;
    int v = (t < SCAN_BLKS && t < b) ? partial[t] : 0;
#pragma unroll
    for (int off = 32; off; off >>= 1) v += __shfl_down(v, off);
    if ((t & 63) == 0) wsum[t >> 6] = v;
    __syncthreads();
    int base = wsum[0] + wsum[1] + wsum[2] + wsum[3];
    int i = b * 256 + t;
    if (i < N) {
        int val = excl[i] + base;
        rowptr[i] = val;
        cursor[i] = val;
    }
    if (i == 0) rowptr[N] = E;
}

__global__ void scatter_kernel(const int* __restrict__ src, const int* __restrict__ dst,
                               int* __restrict__ cursor, int* __restrict__ esrc, int E) {
    int e = blockIdx.x * blockDim.x + threadIdx.x;
    if (e < E) {
        int p = atomicAdd(&cursor[dst[e]], 1);
        esrc[p] = src[e];
    }
}

// ---------------- fp16 MFMA GEMM (32x32x16) ----------------
__global__ __launch_bounds__(256) void gemm_f16(const _Float16* __restrict__ A,
                                                const _Float16* __restrict__ BT,
                                                unsigned char* __restrict__ C8,
                                                float* __restrict__ SPRE,
                                                int M, int Nfeat, int ld, int Kdim, int Cblk,
                                                int ldA, int mode) {
    int id = blockIdx.x;
    int xm = id & 7, q = id >> 3;
    int cb = q % Cblk, rh = q / Cblk;
    int rb = rh * 8 + xm;
    if (rb >= RBLK) return;
    __shared__ __align__(16) _Float16 sA[128 * 64];
    __shared__ __align__(16) _Float16 sB[128 * 64];
    int t = threadIdx.x;
    int row0 = rb * 128, col0 = cb * 128;
    int lane = t & 63, wave = t >> 6;
    int wm = wave >> 1, wn = wave & 1;
    int l31 = lane & 31;
    int lhi = lane >> 5;

    int koff = (mode == 1) ? ((cb >> 1) * 64) : 0;
    const _Float16* gA = A + (size_t)row0 * ldA + koff;
    const _Float16* gB = BT + (size_t)col0 * Kdim;

    int sR[4], sgl[4];
#pragma unroll
    for (int i = 0; i < 4; i++) {
        int m = i * 256 + t;
        sR[i] = m >> 3;
        sgl[i] = (m & 7) ^ (sR[i] & 7);
    }

    f32x16 acc[2][2] = {};

    for (int k0 = 0; k0 < Kdim; k0 += 64) {
        __syncthreads();
#pragma unroll
        for (int i = 0; i < 4; i++) {
            const _Float16* pa = gA + (size_t)sR[i] * ldA + k0 + sgl[i] * 8;
            const _Float16* pb = gB + (size_t)sR[i] * Kdim + k0 + sgl[i] * 8;
            async16(pa, sA + (i * 256 + t) * 8);
            async16(pb, sB + (i * 256 + t) * 8);
        }
        __syncthreads();
#pragma unroll
        for (int kk = 0; kk < 4; kk++) {
            int g = kk * 2 + lhi;
            half8 af[2], bf[2];
#pragma unroll
            for (int mt = 0; mt < 2; mt++) {
                int R = wm * 64 + mt * 32 + l31;
                int gp = g ^ (R & 7);
                af[mt] = *(const half8*)(sA + R * 64 + gp * 8);
            }
#pragma unroll
            for (int nt = 0; nt < 2; nt++) {
                int R = wn * 64 + nt * 32 + l31;
                int gp = g ^ (R & 7);
                bf[nt] = *(const half8*)(sB + R * 64 + gp * 8);
            }
#pragma unroll
            for (int mt = 0; mt < 2; mt++)
#pragma unroll
                for (int nt = 0; nt < 2; nt++)
                    acc[mt][nt] = __builtin_amdgcn_mfma_f32_32x32x16_f16(af[mt], bf[nt], acc[mt][nt], 0, 0, 0);
        }
    }

    int cb32 = col0 + wn * 64 + l31;
    int rb32 = row0 + wm * 64 + 4 * lhi;
    if (mode == 1) {
        _Float16* C16 = (_Float16*)C8;
#pragma unroll
        for (int mt = 0; mt < 2; mt++)
#pragma unroll
            for (int nt = 0; nt < 2; nt++) {
                int gc = cb32 + nt * 32;
                if (gc < Nfeat) {
#pragma unroll
                    for (int r = 0; r < 16; r++) {
                        int gr = rb32 + mt * 32 + (r & 3) + 8 * (r >> 2);
                        if (gr < M) C16[(size_t)gr * ld + gc] = (_Float16)elu1(elu1(acc[mt][nt][r]));
                    }
                }
            }
        return;
    }
#pragma unroll
    for (int mt = 0; mt < 2; mt++)
#pragma unroll
        for (int nt = 0; nt < 2; nt++) {
            int gc = cb32 + nt * 32;
            if (gc < Nfeat) {
#pragma unroll
                for (int r = 0; r < 16; r++) {
                    int gr = rb32 + mt * 32 + (r & 3) + 8 * (r >> 2);
                    if (gr < M) C8[(size_t)gr * ld + gc] = f2fp8(acc[mt][nt][r]);
                }
            } else if (gc < Nfeat + 12) {
                int j = gc - Nfeat;
#pragma unroll
                for (int r = 0; r < 16; r++) {
                    int gr = rb32 + mt * 32 + (r & 3) + 8 * (r >> 2);
                    if (gr < M) SPRE[(size_t)j * N_NODES + gr] = acc[mt][nt][r];
                }
            }
        }
}

// ---------------- layer 1 agg (one wave, 4 heads) + fused L2 pack/wtilde ----------
__global__ __launch_bounds__(256) void aggx1_plus(const int* __restrict__ rowptr,
                                                  const int* __restrict__ esrc,
                                                  const float* __restrict__ SPRE,
                                                  const _Float16* __restrict__ A1,
                                                  _Float16* __restrict__ XB, int N,
                                                  const float* __restrict__ W2,
                                                  const float* __restrict__ a2,
                                                  _Float16* __restrict__ BT16) {
    int bid = blockIdx.x;
    int wv = threadIdx.x >> 6;
    int lane = threadIdx.x & 63;
    if (bid >= AGB) {
        if (bid < AGB + PL2) {
            int pb = bid - AGB;
            pack_bt16_body(W2, BT16, 256, 256, 1024, pb >> 2, (pb & 3) * 256 + threadIdx.x);
        } else {
            int p = (bid - AGB - PL2) * 4 + wv;
            wtilde_pair(W2, a2, BT16, 1024, 1024, 256, 4, 1024, p & 1023, p >> 10, lane);
        }
        return;
    }
    int n = bid * 4 + wv;
    if (n >= N) return;
    int start = rowptr[n], end = rowptr[n + 1];
    int cnt = end - start;
    float sd0 = SPRE[(size_t)4 * N + n];
    float sd1 = SPRE[(size_t)5 * N + n];
    float sd2 = SPRE[(size_t)6 * N + n];
    float sd3 = SPRE[(size_t)7 * N + n];
    const unsigned char* Wb = (const unsigned char*)A1 + 2 * lane;
    float acc0 = 0.f, acc1 = 0.f, acc2 = 0.f, acc3 = 0.f;

    if (cnt <= 64) {
        int e = start + lane;
        bool act = e < end;
        int idx = act ? esrc[e] : 0;
        float g0 = SPRE[idx];
        float g1 = SPRE[(size_t)N + idx];
        float g2 = SPRE[(size_t)2 * N + idx];
        float g3 = SPRE[(size_t)3 * N + idx];
        int voff = idx << 7;

        unsigned short wA[8], wB[8], wC[8], wD[8];
        auto ISSUE = [&](unsigned short (&buf)[8], int base) {
#pragma unroll
            for (int u = 0; u < 8; u++) {
                int off = __builtin_amdgcn_readlane(voff, base + u);
                buf[u] = *(const unsigned short*)(Wb + (unsigned)off);
            }
        };
        ISSUE(wA, 0);
        if (cnt > 8)  ISSUE(wB, 8);
        if (cnt > 16) ISSUE(wC, 16);
        if (cnt > 24) ISSUE(wD, 24);

        float sc0 = -1e30f, sc1 = -1e30f, sc2 = -1e30f, sc3 = -1e30f;
        if (act) {
            sc0 = g0 + sd0; sc0 = sc0 > 0.f ? sc0 : ALPHA * sc0;
            sc1 = g1 + sd1; sc1 = sc1 > 0.f ? sc1 : ALPHA * sc1;
            sc2 = g2 + sd2; sc2 = sc2 > 0.f ? sc2 : ALPHA * sc2;
            sc3 = g3 + sd3; sc3 = sc3 > 0.f ? sc3 : ALPHA * sc3;
        }
        float m0 = sc0, m1 = sc1, m2 = sc2, m3 = sc3;
#pragma unroll
        for (int off = 1; off < 64; off <<= 1) {
            m0 = fmaxf(m0, __shfl_xor(m0, off));
            m1 = fmaxf(m1, __shfl_xor(m1, off));
            m2 = fmaxf(m2, __shfl_xor(m2, off));
            m3 = fmaxf(m3, __shfl_xor(m3, off));
        }
        float p0 = act ? __expf(sc0 - m0) : 0.f;
        float p1 = act ? __expf(sc1 - m1) : 0.f;
        float p2 = act ? __expf(sc2 - m2) : 0.f;
        float p3 = act ? __expf(sc3 - m3) : 0.f;
        float s0 = p0, s1 = p1, s2 = p2, s3 = p3;
#pragma unroll
        for (int off = 1; off < 64; off <<= 1) {
            s0 += __shfl_xor(s0, off);
            s1 += __shfl_xor(s1, off);
            s2 += __shfl_xor(s2, off);
            s3 += __shfl_xor(s3, off);
        }
        p0 *= 1.f / (s0 + GAT_EPS);
        p1 *= 1.f / (s1 + GAT_EPS);
        p2 *= 1.f / (s2 + GAT_EPS);
        p3 *= 1.f / (s3 + GAT_EPS);

        auto CONSUME = [&](unsigned short (&buf)[8], int base) {
#pragma unroll
            for (int u = 0; u < 8; u++) {
                float xv = (float)(*(const _Float16*)&buf[u]);
                acc0 += rdlanef(p0, base + u) * xv;
                acc1 += rdlanef(p1, base + u) * xv;
                acc2 += rdlanef(p2, base + u) * xv;
                acc3 += rdlanef(p3, base + u) * xv;
            }
        };
        __builtin_amdgcn_s_setprio(1);
        CONSUME(wA, 0);
        if (cnt > 8)  { if (cnt > 32) ISSUE(wA, 32); CONSUME(wB, 8); }
        if (cnt > 16) { if (cnt > 40) ISSUE(wB, 40); CONSUME(wC, 16); }
        if (cnt > 24) { if (cnt > 48) ISSUE(wC, 48); CONSUME(wD, 24); }
        if (cnt > 32) { if (cnt > 56) ISSUE(wD, 56); CONSUME(wA, 32); }
        if (cnt > 40) CONSUME(wB, 40);
        if (cnt > 48) CONSUME(wC, 48);
        if (cnt > 56) CONSUME(wD, 56);
        __builtin_amdgcn_s_setprio(0);
    } else {
#pragma unroll
        for (int h = 0; h < 4; h++) {
            const float* ss = SPRE + (size_t)h * N;
            float sd = SPRE[(size_t)(4 + h) * N + n];
            float m = -1e30f, s = 0.f;
            for (int e0 = start; e0 < end; e0 += 64) {
                int e = e0 + lane;
                bool act = e < end;
                int idx = act ? esrc[e] : 0;
                float sc = -1e30f;
                if (act) {
                    sc = ss[idx] + sd;
                    sc = sc > 0.f ? sc : ALPHA * sc;
                }
                float mn = fmaxf(m, sc);
                s = s * __expf(m - mn) + (act ? __expf(sc - mn) : 0.f);
                m = mn;
            }
            float lm = m;
#pragma unroll
            for (int off = 1; off < 64; off <<= 1) m = fmaxf(m, __shfl_xor(m, off));
            float ptil = s * __expf(lm - m);
            s = ptil;
#pragma unroll
            for (int off = 1; off < 64; off <<= 1) s += __shfl_xor(s, off);
            float inv = 1.f / (s + GAT_EPS);
            float acch = 0.f;
            for (int e0 = start; e0 < end; e0 += 64) {
                int e = e0 + lane;
                bool act = e < end;
                int idx = act ? esrc[e] : 0;
                float sc = -1e30f;
                if (act) {
                    sc = ss[idx] + sd;
                    sc = sc > 0.f ? sc : ALPHA * sc;
                }
                float p = act ? __expf(sc - m) * inv : 0.f;
                int cn = end - e0; if (cn > 64) cn = 64;
                for (int j = 0; j < cn; j++) {
                    int ij = __builtin_amdgcn_readlane(idx, j);
                    float pj = rdlanef(p, j);
                    unsigned short w = *(const unsigned short*)(Wb + ((size_t)(unsigned)ij << 7));
                    acch += pj * (float)(*(const _Float16*)&w);
                }
            }
            if (h == 0) acc0 = acch;
            else if (h == 1) acc1 = acch;
            else if (h == 2) acc2 = acch;
            else acc3 = acch;
        }
    }

    size_t ob = (size_t)n * 256 + lane;
    XB[ob]       = (_Float16)acc0;
    XB[ob + 64]  = (_Float16)acc1;
    XB[ob + 128] = (_Float16)acc2;
    XB[ob + 192] = (_Float16)acc3;
}

// ---------------- layer 2 att+agg (broadcast 4-deep) + fused L3 pack/wtilde ----------
__global__ __launch_bounds__(256) void attagg256_plus(const int* __restrict__ rowptr,
                                                      const int* __restrict__ esrc,
                                                      const float* __restrict__ SPRE,
                                                      const unsigned char* __restrict__ WH8,
                                                      _Float16* __restrict__ X16,
                                                      int use_skip, int N,
                                                      const float* __restrict__ W3,
                                                      const float* __restrict__ a3,
                                                      _Float16* __restrict__ BT16) {
    int bid = blockIdx.x;
    int h = threadIdx.x >> 6;
    int lane = threadIdx.x & 63;
    if (bid >= N_NODES) {
        if (bid < N_NODES + PL3) {
            int pb = bid - N_NODES;
            pack_bt16_body(W3, BT16, 121, 124, 744, pb >> 2, (pb & 3) * 256 + threadIdx.x);
        } else {
            int p = (bid - N_NODES - PL3) * 4 + h;
            wtilde_pair(W3, a3, BT16, 1024, 1024, 121, 6, 744, p & 1023, p >> 10, lane);
        }
        return;
    }
    int n = bid;
    int start = rowptr[n], end = rowptr[n + 1];
    int cnt = end - start;
    const float* ss = SPRE + (size_t)h * N;
    float sd = SPRE[(size_t)(4 + h) * N + n];
    const unsigned char* Wb = WH8 + h * 256 + lane * 4;
    size_t o = (size_t)n * 1024 + h * 256 + lane * 4;
    half4t sk = {};
    if (use_skip) sk = *(const half4t*)(X16 + o);   // prefetch skip
    float a0 = 0.f, a1 = 0.f, a2 = 0.f, a3v = 0.f;

    if (cnt <= 64) {
        int e = start + lane;
        bool act = e < end;
        int idx = act ? esrc[e] : 0;
        float sv = ss[idx];

        unsigned int wA[8], wB[8], wC[8], wD[8];
        auto ISSUE = [&](unsigned int (&buf)[8], int base) {
#pragma unroll
            for (int u = 0; u < 8; u++) {
                int ij = __builtin_amdgcn_readlane(idx, base + u);
                buf[u] = *(const unsigned int*)(Wb + ((size_t)(unsigned)ij << 10));
            }
        };
        ISSUE(wA, 0);
        if (cnt > 8)  ISSUE(wB, 8);
        if (cnt > 16) ISSUE(wC, 16);
        if (cnt > 24) ISSUE(wD, 24);

        float sc = -1e30f;
        if (act) {
            sc = sv + sd;
            sc = sc > 0.f ? sc : ALPHA * sc;
        }
        float m = sc;
#pragma unroll
        for (int off = 1; off < 64; off <<= 1) m = fmaxf(m, __shfl_xor(m, off));
        float ptil = act ? __expf(sc - m) : 0.f;
        float s = ptil;
#pragma unroll
        for (int off = 1; off < 64; off <<= 1) s += __shfl_xor(s, off);
        float p = ptil * (1.f / (s + GAT_EPS));

        auto CONSUME = [&](unsigned int (&buf)[8], int base) {
#pragma unroll
            for (int u = 0; u < 8; u++) {
                float pj = rdlanef(p, base + u);
                f32x2 lo = cvt8<false>(buf[u]);
                f32x2 hi = cvt8<true>(buf[u]);
                a0 += pj * lo.x; a1 += pj * lo.y; a2 += pj * hi.x; a3v += pj * hi.y;
            }
        };
        __builtin_amdgcn_s_setprio(1);
        CONSUME(wA, 0);
        if (cnt > 8)  { if (cnt > 32) ISSUE(wA, 32); CONSUME(wB, 8); }
        if (cnt > 16) { if (cnt > 40) ISSUE(wB, 40); CONSUME(wC, 16); }
        if (cnt > 24) { if (cnt > 48) ISSUE(wC, 48); CONSUME(wD, 24); }
        if (cnt > 32) { if (cnt > 56) ISSUE(wD, 56); CONSUME(wA, 32); }
        if (cnt > 40) CONSUME(wB, 40);
        if (cnt > 48) CONSUME(wC, 48);
        if (cnt > 56) CONSUME(wD, 56);
        __builtin_amdgcn_s_setprio(0);
    } else {
        float m = -1e30f, s = 0.f;
        int sidx = 0; float ssc = -1e30f;
        for (int e0 = start; e0 < end; e0 += 64) {
            int e = e0 + lane;
            bool act = e < end;
            int idx = act ? esrc[e] : 0;
            float sc = -1e30f;
            if (act) {
                sc = ss[idx] + sd;
                sc = sc > 0.f ? sc : ALPHA * sc;
            }
            sidx = idx; ssc = sc;
            float mn = fmaxf(m, sc);
            s = s * __expf(m - mn) + (act ? __expf(sc - mn) : 0.f);
            m = mn;
        }
        float lm = m;
#pragma unroll
        for (int off = 1; off < 64; off <<= 1) m = fmaxf(m, __shfl_xor(m, off));
        float ptil = s * __expf(lm - m);
        s = ptil;
#pragma unroll
        for (int off = 1; off < 64; off <<= 1) s += __shfl_xor(s, off);
        float inv = 1.f / (s + GAT_EPS);

        int lastStart = start + (((end - start - 1) >> 6) << 6);
        for (int e0 = start; e0 < end; e0 += 64) {
            int e = e0 + lane;
            bool act = e < end;
            int idx; float p;
            if (e0 == lastStart) {
                idx = sidx;
                p = act ? __expf(ssc - m) * inv : 0.f;
            } else {
                idx = act ? esrc[e] : 0;
                float sc = -1e30f;
                if (act) {
                    sc = ss[idx] + sd;
                    sc = sc > 0.f ? sc : ALPHA * sc;
                }
                p = act ? __expf(sc - m) * inv : 0.f;
            }
            int cn = end - e0; if (cn > 64) cn = 64;
            for (int j = 0; j < cn; j++) {
                int ij = __builtin_amdgcn_readlane(idx, j);
                float pj = rdlanef(p, j);
                unsigned int w = *(const unsigned int*)(Wb + (size_t)ij * 1024);
                f32x2 lo = cvt8<false>(w);
                f32x2 hi = cvt8<true>(w);
                a0 += pj * lo.x; a1 += pj * lo.y; a2 += pj * hi.x; a3v += pj * hi.y;
            }
        }
    }

    float v0, v1, v2, v3;
    if (use_skip) {
        v0 = elu1(elu1(a0) + (float)sk.x);
        v1 = elu1(elu1(a1) + (float)sk.y);
        v2 = elu1(elu1(a2) + (float)sk.z);
        v3 = elu1(elu1(a3v) + (float)sk.w);
    } else {
        v0 = elu1(elu1(a0)); v1 = elu1(elu1(a1));
        v2 = elu1(elu1(a2)); v3 = elu1(elu1(a3v));
    }
    half4t r;
    r.x = (_Float16)v0; r.y = (_Float16)v1; r.z = (_Float16)v2; r.w = (_Float16)v3;
    *(half4t*)(X16 + o) = r;
}

// ---------------- layer 3 att+agg (broadcast 4-deep, known-best) ----------
__global__ __launch_bounds__(384) void attagg726_kernel(const int* __restrict__ rowptr,
                                                        const int* __restrict__ esrc,
                                                        const float* __restrict__ SPRE,
                                                        const unsigned char* __restrict__ WH8,
                                                        float* __restrict__ out, int N) {
    __shared__ float part[6][124];
    int n = blockIdx.x;
    int t = threadIdx.x;
    int h = t >> 6;
    int lane = t & 63;
    int start = rowptr[n], end = rowptr[n + 1];
    int cnt = end - start;
    const float* ss = SPRE + (size_t)h * N;
    float sd = SPRE[(size_t)(6 + h) * N + n];
    const unsigned char* Wb = WH8 + h * 124 + 2 * lane;
    float a0 = 0.f, a1 = 0.f;

    if (cnt <= 64) {
        int e = start + lane;
        bool act = e < end;
        int idx = act ? esrc[e] : 0;
        float sv = ss[idx];

        unsigned short wA[8], wB[8], wC[8], wD[8];
        auto ISSUE = [&](unsigned short (&buf)[8], int base) {
#pragma unroll
            for (int u = 0; u < 8; u++) {
                int ij = __builtin_amdgcn_readlane(idx, base + u);
                buf[u] = *(const unsigned short*)(Wb + (size_t)(unsigned)ij * 768u);
            }
        };
        ISSUE(wA, 0);
        if (cnt > 8)  ISSUE(wB, 8);
        if (cnt > 16) ISSUE(wC, 16);
        if (cnt > 24) ISSUE(wD, 24);

        float sc = -1e30f;
        if (act) {
            sc = sv + sd;
            sc = sc > 0.f ? sc : ALPHA * sc;
        }
        float m = sc;
#pragma unroll
        for (int off = 1; off < 64; off <<= 1) m = fmaxf(m, __shfl_xor(m, off));
        float ptil = act ? __expf(sc - m) : 0.f;
        float s = ptil;
#pragma unroll
        for (int off = 1; off < 64; off <<= 1) s += __shfl_xor(s, off);
        float p = ptil * (1.f / (s + GAT_EPS));

        auto CONSUME = [&](unsigned short (&buf)[8], int base) {
#pragma unroll
            for (int u = 0; u < 8; u++) {
                float pj = rdlanef(p, base + u);
                f32x2 f = cvt8<false>(buf[u]);
                a0 += pj * f.x; a1 += pj * f.y;
            }
        };
        __builtin_amdgcn_s_setprio(1);
        CONSUME(wA, 0);
        if (cnt > 8)  { if (cnt > 32) ISSUE(wA, 32); CONSUME(wB, 8); }
        if (cnt > 16) { if (cnt > 40) ISSUE(wB, 40); CONSUME(wC, 16); }
        if (cnt > 24) { if (cnt > 48) ISSUE(wC, 48); CONSUME(wD, 24); }
        if (cnt > 32) { if (cnt > 56) ISSUE(wD, 56); CONSUME(wA, 32); }
        if (cnt > 40) CONSUME(wB, 40);
        if (cnt > 48) CONSUME(wC, 48);
        if (cnt > 56) CONSUME(wD, 56);
        __builtin_amdgcn_s_setprio(0);
    } else {
        float m = -1e30f, s = 0.f;
        int sidx = 0; float ssc = -1e30f;
        for (int e0 = start; e0 < end; e0 += 64) {
            int e = e0 + lane;
            bool act = e < end;
            int idx = act ? esrc[e] : 0;
            float sc = -1e30f;
            if (act) {
                sc = ss[idx] + sd;
                sc = sc > 0.f ? sc : ALPHA * sc;
            }
            sidx = idx; ssc = sc;
            float mn = fmaxf(m, sc);
            s = s * __expf(m - mn) + (act ? __expf(sc - mn) : 0.f);
            m = mn;
        }
        float lm = m;
#pragma unroll
        for (int off = 1; off < 64; off <<= 1) m = fmaxf(m, __shfl_xor(m, off));
        float ptil = s * __expf(lm - m);
        s = ptil;
#pragma unroll
        for (int off = 1; off < 64; off <<= 1) s += __shfl_xor(s, off);
        float inv = 1.f / (s + GAT_EPS);

        int lastStart = start + (((end - start - 1) >> 6) << 6);
        for (int e0 = start; e0 < end; e0 += 64) {
            int e = e0 + lane;
            bool act = e < end;
            int idx; float p;
            if (e0 == lastStart) {
                idx = sidx;
                p = act ? __expf(ssc - m) * inv : 0.f;
            } else {
                idx = act ? esrc[e] : 0;
                float sc = -1e30f;
                if (act) {
                    sc = ss[idx] + sd;
                    sc = sc > 0.f ? sc : ALPHA * sc;
                }
                p = act ? __expf(sc - m) * inv : 0.f;
            }
            int cn = end - e0; if (cn > 64) cn = 64;
            if (lane < 62) {
                for (int j = 0; j < cn; j++) {
                    int ij = __builtin_amdgcn_readlane(idx, j);
                    float pj = rdlanef(p, j);
                    unsigned short w = *(const unsigned short*)(Wb + (size_t)ij * 768);
                    f32x2 f = cvt8<false>(w);
                    a0 += pj * f.x; a1 += pj * f.y;
                }
            }
        }
    }

    if (lane < 62) {
        part[h][2 * lane]     = a0;
        part[h][2 * lane + 1] = a1;
    }
    __syncthreads();
    if (t < 121) {
        float tot = (part[0][t] + part[1][t] + part[2][t] +
                     part[3][t] + part[4][t] + part[5][t]) * (1.f / 6.f);
        out[(size_t)n * 121 + t] = 1.f / (1.f + __expf(-tot));
    }
}

extern "C" void kernel_launch(void* const* d_in, const int* in_sizes, int n_in,
                              void* d_out, int out_size, void* d_ws, size_t ws_size,
                              hipStream_t stream) {
    const float* x  = (const float*)d_in[0];
    const int*   ei = (const int*)d_in[1];
    const float* W1 = (const float*)d_in[2];
    const float* a1 = (const float*)d_in[3];
    const float* W2 = (const float*)d_in[4];
    const float* a2 = (const float*)d_in[5];
    const float* W3 = (const float*)d_in[6];
    const float* a3 = (const float*)d_in[7];
    float* out = (float*)d_out;
    const int N = N_NODES, E = N_EDGES;
    const int* src = ei;
    const int* dst = ei + E;

    char* ws = (char*)d_ws;
    size_t off = 0;
    auto alloc = [&](size_t b) { size_t o = off; off += (b + 255) & ~(size_t)255; return o; };
    _Float16* X16  = (_Float16*)(ws + alloc((size_t)MPAD * 1024 * 2));  // x1 then x2 (fp16)
    unsigned char* WH8 = (unsigned char*)(ws + alloc((size_t)MPAD * 1024)); // per-layer Wh (fp8)
    _Float16* BT16 = (_Float16*)(ws + alloc((size_t)BT_ROWS * 1024 * 2));
    _Float16* A1   = (_Float16*)(ws + alloc((size_t)MPAD * 64 * 2));
    _Float16* BT1  = (_Float16*)(ws + alloc((size_t)BT_ROWS * 64 * 2));
    _Float16* XB   = (_Float16*)(ws + alloc((size_t)MPAD * 256 * 2));  // layer-1 xbar
    _Float16* BTS  = (_Float16*)(ws + alloc((size_t)128 * 64 * 2));    // layer-1 score cols
    float* SPRE   = (float*)(ws + alloc((size_t)12 * N * 4));
    int*   rowptr = (int*)(ws + alloc((size_t)(N + 1) * 4));
    int*   cursor = (int*)(ws + alloc((size_t)N * 4));
    int*   counts = (int*)(ws + alloc((size_t)N * 4));
    int*   excl   = (int*)(ws + alloc((size_t)N * 4));
    int*   partial= (int*)(ws + alloc((size_t)SCAN_BLKS * 4));
    int*   esrc   = (int*)(ws + alloc((size_t)E * 4));

    // CSR build + layer-1 packs (fused grid)
    hipMemsetAsync(counts, 0, (size_t)N * 4, stream);
    hist_plus<<<HB1 + PXB + PB1 + WT1B, 256, 0, stream>>>(dst, counts, E, x, A1, W1, BT1, a1, BTS);
    scan1_kernel<<<SCAN_BLKS, 256, 0, stream>>>(counts, excl, partial, N);
    scan3_kernel<<<SCAN_BLKS, 256, 0, stream>>>(excl, partial, rowptr, cursor, N, E);
    scatter_kernel<<<(E + 255) / 256, 256, 0, stream>>>(src, dst, cursor, esrc, E);
    hipMemsetAsync(X16 + (size_t)N * 1024, 0, (size_t)(MPAD - N) * 1024 * 2, stream);
    hipMemsetAsync(XB + (size_t)N * 256, 0, (size_t)(MPAD - N) * 256 * 2, stream);

    // ---- layer 1: scores; aggregate x (L2-resident) + fused L2 pack/wtilde; blockdiag ----
    gemm_f16<<<8 * RHI * 1, 256, 0, stream>>>(A1, BTS, WH8, SPRE, N, 0, 1024, 64, 1, 64, 0);
    aggx1_plus<<<AGB + PL2 + WT2B, 256, 0, stream>>>(rowptr, esrc, SPRE, A1, XB, N, W2, a2, BT16);
    gemm_f16<<<8 * RHI * 8, 256, 0, stream>>>(XB, BT1, (unsigned char*)X16, SPRE, N, 1024, 1024, 64, 8, 256, 1);

    // ---- layer 2: GEMM; att+agg + fused L3 pack/wtilde ----
    gemm_f16<<<8 * RHI * 9, 256, 0, stream>>>(X16, BT16, WH8, SPRE, N, 1024, 1024, 1024, 9, 1024, 0);
    attagg256_plus<<<N_NODES + PL3 + WT3B, 256, 0, stream>>>(rowptr, esrc, SPRE, WH8, X16, 1, N, W3, a3, BT16);

    // ---- layer 3: GEMM; att+agg + mean + sigmoid ----
    gemm_f16<<<8 * RHI * 6, 256, 0, stream>>>(X16, BT16, WH8, SPRE, N, 744, 768, 1024, 6, 1024, 0);
    attagg726_kernel<<<N, 384, 0, stream>>>(rowptr, esrc, SPRE, WH8, out, N);
}